// Round 4
// baseline (242.074 us; speedup 1.0000x reference)
//
#include <hip/hip_runtime.h>

typedef __attribute__((ext_vector_type(8))) short short8;
typedef __attribute__((ext_vector_type(4))) float f32x4;

#define SCALE2 0.06375871571f   // (1/sqrt(512)) * log2(e)

__device__ __forceinline__ float bfu(unsigned short u){
  return __uint_as_float(((unsigned int)u) << 16);
}
__device__ __forceinline__ unsigned short f2b(float x){   // RNE
  unsigned int b = __float_as_uint(x);
  return (unsigned short)((b + 0x7fffu + ((b>>16)&1u)) >> 16);
}
// 8 contiguous f32 -> 8 bf16 packed in a uint4
__device__ __forceinline__ uint4 pack8(const float* f){
  float4 a = *(const float4*)f, b = *(const float4*)(f+4);
  uint4 r;
  r.x = (unsigned)f2b(a.x) | ((unsigned)f2b(a.y)<<16);
  r.y = (unsigned)f2b(a.z) | ((unsigned)f2b(a.w)<<16);
  r.z = (unsigned)f2b(b.x) | ((unsigned)f2b(b.y)<<16);
  r.w = (unsigned)f2b(b.z) | ((unsigned)f2b(b.w)<<16);
  return r;
}

// ---------------- fused input prep: weight transpose + q/k convert ----------------
__global__ __launch_bounds__(256) void prep_inputs(
    const float* Wq, const float* Wk, const float* Wv, const float* Wo,
    const float* q, const float* k, unsigned short* wt, unsigned short* qk_dst)
{
  const int id = blockIdx.x, t = threadIdx.x;
  if (id < 256){
    const int m = id >> 6;
    const float* W = (m==0)?Wq:(m==1)?Wk:(m==2)?Wv:Wo;
    unsigned short* dst = wt + (long)m*262144;
    __shared__ unsigned short tile[64][72];
    const int n0 = ((id>>3)&7)*64, k0 = (id&7)*64;
    {
      int r = t>>2, c0 = (t&3)*16;
      uint4 u0 = pack8(W + (long)(k0+r)*512 + n0 + c0);
      uint4 u1 = pack8(W + (long)(k0+r)*512 + n0 + c0 + 8);
      unsigned short* us0 = (unsigned short*)&u0;
      unsigned short* us1 = (unsigned short*)&u1;
      #pragma unroll
      for (int i=0;i<8;++i) tile[c0+i][r] = us0[i];
      #pragma unroll
      for (int i=0;i<8;++i) tile[c0+8+i][r] = us1[i];
    }
    __syncthreads();
    {
      int n = t>>2, ks = (t&3)*16;
      *(uint4*)(dst + (long)(n0+n)*512 + k0 + ks)     = *(uint4*)&tile[n][ks];
      *(uint4*)(dst + (long)(n0+n)*512 + k0 + ks + 8) = *(uint4*)&tile[n][ks+8];
    }
  } else {
    long i = ((long)(id-256)*256 + t)*8;
    const float* src = (i < 4194304) ? q + i : k + (i - 4194304);
    *(uint4*)(qk_dst + i) = pack8(src);
  }
}

// ---------------- QKV projection (bf16 MFMA, dbuf LDS, 1 barrier/iter) ----------------
__global__ __launch_bounds__(256) void proj_mfma(
    const unsigned short* qin, const unsigned short* kin, const unsigned short* wt,
    const float* bq, const float* bk, const float* bv,
    unsigned short* q_bf, unsigned short* k_bf, unsigned short* vt_bf)
{
  const int mat = blockIdx.z;
  const unsigned short* A = (mat==0)? qin : kin;
  const unsigned short* Wt = wt + (long)mat*262144;
  const float* bias = (mat==0)?bq:(mat==1)?bk:bv;
  const int row0 = blockIdx.y*128, col0 = blockIdx.x*128;
  __shared__ unsigned short As[2][128][40];
  __shared__ unsigned short Ws[2][128][40];
  const int t = threadIdx.x;
  const int lane = t & 63, wid = t >> 6;
  const int ln = lane & 15, quad = lane >> 4;
  const int wy = wid >> 1, wx = wid & 1;
  f32x4 acc[4][4];
  #pragma unroll
  for (int i=0;i<4;++i){
    #pragma unroll
    for (int j=0;j<4;++j) acc[i][j] = (f32x4){0.f,0.f,0.f,0.f};
  }
  const int sr = t>>1, sk0 = (t&1)*16;
  const unsigned short* Arow = A  + (long)(row0+sr)*512 + sk0;
  const unsigned short* Wrow = Wt + (long)(col0+sr)*512 + sk0;
  uint4 a0 = *(const uint4*)(Arow);
  uint4 a1 = *(const uint4*)(Arow + 8);
  uint4 w0 = *(const uint4*)(Wrow);
  uint4 w1 = *(const uint4*)(Wrow + 8);
  *(uint4*)&As[0][sr][sk0]   = a0;
  *(uint4*)&As[0][sr][sk0+8] = a1;
  *(uint4*)&Ws[0][sr][sk0]   = w0;
  *(uint4*)&Ws[0][sr][sk0+8] = w1;
  __syncthreads();
  for (int it=0; it<16; ++it){
    const int cur = it & 1;
    if (it < 15){
      a0 = *(const uint4*)(Arow + (it+1)*32);
      a1 = *(const uint4*)(Arow + (it+1)*32 + 8);
      w0 = *(const uint4*)(Wrow + (it+1)*32);
      w1 = *(const uint4*)(Wrow + (it+1)*32 + 8);
    }
    short8 a[4], b[4];
    #pragma unroll
    for (int mt=0;mt<4;++mt) a[mt] = *(const short8*)&As[cur][wy*64+mt*16+ln][quad*8];
    #pragma unroll
    for (int nt=0;nt<4;++nt) b[nt] = *(const short8*)&Ws[cur][wx*64+nt*16+ln][quad*8];
    #pragma unroll
    for (int mt=0;mt<4;++mt){
      #pragma unroll
      for (int nt=0;nt<4;++nt)
        acc[mt][nt] = __builtin_amdgcn_mfma_f32_16x16x32_bf16(a[mt], b[nt], acc[mt][nt], 0,0,0);
    }
    if (it < 15){
      *(uint4*)&As[cur^1][sr][sk0]   = a0;
      *(uint4*)&As[cur^1][sr][sk0+8] = a1;
      *(uint4*)&Ws[cur^1][sr][sk0]   = w0;
      *(uint4*)&Ws[cur^1][sr][sk0+8] = w1;
    }
    __syncthreads();
  }
  float bias_v[4];
  #pragma unroll
  for (int nt=0;nt<4;++nt) bias_v[nt] = bias[col0 + wx*64 + nt*16 + ln];
  if (mat < 2){
    unsigned short* dst = (mat==0)? q_bf : k_bf;
    #pragma unroll
    for (int mt=0;mt<4;++mt){
      int row = row0 + wy*64 + mt*16 + quad*4;
      #pragma unroll
      for (int nt=0;nt<4;++nt){
        int col = col0 + wx*64 + nt*16 + ln;
        #pragma unroll
        for (int r=0;r<4;++r)
          dst[(long)(row+r)*512 + col] = f2b(acc[mt][nt][r] + bias_v[nt]);
      }
    }
  } else {
    #pragma unroll
    for (int mt=0;mt<4;++mt){
      int row = row0 + wy*64 + mt*16 + quad*4;   // token base, 4-aligned
      int bb = row >> 10, sk = row & 1023;
      #pragma unroll
      for (int nt=0;nt<4;++nt){
        int col = col0 + wx*64 + nt*16 + ln;
        int h = col >> 6, dd = col & 63;
        uint2 pk2; unsigned short* pp = (unsigned short*)&pk2;
        #pragma unroll
        for (int r=0;r<4;++r) pp[r] = f2b(acc[mt][nt][r] + bias_v[nt]);
        *(uint2*)(vt_bf + (((long)((bb*8+h)*64+dd)) << 10) + sk) = pk2;
      }
    }
  }
}

// ---------------- flash attention: no K/V LDS staging (L1/L2 direct), no barriers ----------------
// Waves are fully independent: each wave owns 32 q-rows (2 strips of 16). K/V fragments are
// loaded straight from global (L2-resident: 256KB per (b,h); all 4 waves read identical lines
// -> L1 hits). S^T via mfma(K,Q) so q is lane-local; softmax in-register; P goes through a
// wave-private LDS buffer (Pw) with vectorized b64 writes at true k columns and standard
// A-fragment b128 reads (the R3-verified mechanics). K is register-double-buffered (next iter
// prefetched); V is issued at iter top and consumed after QK+softmax (~400cy) -> L2 latency hidden.
__global__ __launch_bounds__(256, 2) void attn_mfma(
    const unsigned short* q_bf, const unsigned short* k_bf, const unsigned short* vt_bf,
    const float* pres_q, const float* pres_k, unsigned short* o_bf)
{
  const int bx = blockIdx.x;
  const int b = bx >> 3, h = bx & 7;
  const int q0 = blockIdx.y * 128;
  const int t = threadIdx.x;
  const int lane = t & 63, wid = t >> 6, ln = lane & 15, quad = lane >> 4;
  __shared__ unsigned short Pw[4][32][72];

  const unsigned short* Kb  = k_bf  + ((long)b*1024)*512 + h*64;
  const unsigned short* Vb  = vt_bf + (((long)(b*8+h)) << 16);
  const float* pkb = pres_k + b*1024;

  short8 aq[2][2];
  float av[2], mval[2];
  #pragma unroll
  for (int st=0;st<2;++st){
    int qi = q0 + wid*32 + st*16 + ln;
    const unsigned short* qrow = q_bf + ((long)(b*1024 + qi))*512 + h*64;
    aq[st][0] = *(const short8*)(qrow + quad*8);
    aq[st][1] = *(const short8*)(qrow + 32 + quad*8);
    av[st]   = SCALE2 * pres_q[b*1024 + qi];
    mval[st] = (av[st] == 0.f) ? 0.f : -43.f;
  }
  f32x4 oacc[2][4];
  #pragma unroll
  for (int st=0;st<2;++st){
    #pragma unroll
    for (int i=0;i<4;++i) oacc[st][i] = (f32x4){0.f,0.f,0.f,0.f};
  }
  float lsum[2] = {0.f, 0.f};

  // K fragments for it=0
  short8 kf0[4], kf1[4];
  #pragma unroll
  for (int kt=0;kt<4;++kt){
    const unsigned short* kp = Kb + ((long)(kt*16+ln))*512 + quad*8;
    kf0[kt] = *(const short8*)kp;
    kf1[kt] = *(const short8*)(kp+32);
  }

  for (int it=0; it<16; ++it){
    const int k0 = it*64;
    // V fragments (current iter) — issued early, consumed after QK+softmax
    short8 vf0[4], vf1[4];
    #pragma unroll
    for (int dt=0;dt<4;++dt){
      const unsigned short* vp = Vb + (((long)(dt*16+ln)) << 10) + k0 + quad*8;
      vf0[dt] = *(const short8*)vp;
      vf1[dt] = *(const short8*)(vp+32);
    }
    // presence-k (current iter); same 16B for all ln within a quad -> L1 broadcast
    float4 pk4[4];
    #pragma unroll
    for (int kt=0;kt<4;++kt)
      pk4[kt] = *(const float4*)(pkb + k0 + kt*16 + quad*4);
    // K prefetch (next iter)
    short8 nk0[4], nk1[4];
    if (it < 15){
      #pragma unroll
      for (int kt=0;kt<4;++kt){
        const unsigned short* kp = Kb + ((long)(k0+64+kt*16+ln))*512 + quad*8;
        nk0[kt] = *(const short8*)kp;
        nk1[kt] = *(const short8*)(kp+32);
      }
    }
    // per-strip: S^T = K Q^T, softmax, Pw write
    #pragma unroll
    for (int st=0;st<2;++st){
      f32x4 sc[4];
      #pragma unroll
      for (int kt=0;kt<4;++kt) sc[kt] = (f32x4){0.f,0.f,0.f,0.f};
      __builtin_amdgcn_s_setprio(1);
      #pragma unroll
      for (int kt=0;kt<4;++kt){
        sc[kt] = __builtin_amdgcn_mfma_f32_16x16x32_bf16(kf0[kt], aq[st][0], sc[kt], 0,0,0);
        sc[kt] = __builtin_amdgcn_mfma_f32_16x16x32_bf16(kf1[kt], aq[st][1], sc[kt], 0,0,0);
      }
      __builtin_amdgcn_s_setprio(0);
      #pragma unroll
      for (int kt=0;kt<4;++kt){
        float x0 = __builtin_fmaf(pk4[kt].x, __builtin_fmaf(sc[kt][0], av[st], -mval[st]), mval[st]);
        float x1 = __builtin_fmaf(pk4[kt].y, __builtin_fmaf(sc[kt][1], av[st], -mval[st]), mval[st]);
        float x2 = __builtin_fmaf(pk4[kt].z, __builtin_fmaf(sc[kt][2], av[st], -mval[st]), mval[st]);
        float x3 = __builtin_fmaf(pk4[kt].w, __builtin_fmaf(sc[kt][3], av[st], -mval[st]), mval[st]);
        float e0 = __builtin_amdgcn_exp2f(x0);
        float e1 = __builtin_amdgcn_exp2f(x1);
        float e2 = __builtin_amdgcn_exp2f(x2);
        float e3 = __builtin_amdgcn_exp2f(x3);
        lsum[st] += (e0+e1)+(e2+e3);
        uint2 w;
        w.x = (unsigned)f2b(e0) | ((unsigned)f2b(e1)<<16);
        w.y = (unsigned)f2b(e2) | ((unsigned)f2b(e3)<<16);
        *(uint2*)&Pw[wid][st*16+ln][kt*16 + quad*4] = w;
      }
    }
    // O += P V
    #pragma unroll
    for (int st=0;st<2;++st){
      short8 ap0 = *(const short8*)&Pw[wid][st*16+ln][quad*8];
      short8 ap1 = *(const short8*)&Pw[wid][st*16+ln][32 + quad*8];
      __builtin_amdgcn_s_setprio(1);
      #pragma unroll
      for (int dt=0;dt<4;++dt){
        oacc[st][dt] = __builtin_amdgcn_mfma_f32_16x16x32_bf16(ap0, vf0[dt], oacc[st][dt], 0,0,0);
        oacc[st][dt] = __builtin_amdgcn_mfma_f32_16x16x32_bf16(ap1, vf1[dt], oacc[st][dt], 0,0,0);
      }
      __builtin_amdgcn_s_setprio(0);
    }
    if (it < 15){
      #pragma unroll
      for (int kt=0;kt<4;++kt){ kf0[kt] = nk0[kt]; kf1[kt] = nk1[kt]; }
    }
  }
  // epilogue: o = qh + (P V)/l  (bf16 out)
  #pragma unroll
  for (int st=0;st<2;++st){
    float l = lsum[st];
    l += __shfl_xor(l, 16);
    l += __shfl_xor(l, 32);
    #pragma unroll
    for (int r=0;r<4;++r){
      float lr = __shfl(l, quad*4 + r);
      float inv = 1.f / lr;
      int ql = q0 + wid*32 + st*16 + quad*4 + r;
      long base = ((long)(b*1024 + ql))*512 + h*64;
      #pragma unroll
      for (int dt=0;dt<4;++dt){
        float qh = bfu(q_bf[base + dt*16 + ln]);
        o_bf[base + dt*16 + ln] = f2b(qh + oacc[st][dt][r]*inv);
      }
    }
  }
}

// ---------------- layernorm (wave per row), bf16 input ----------------
__global__ __launch_bounds__(256) void ln_kernel(
    const unsigned short* in, void* outp, int mode, const float* g, const float* bvec)
{
  const int row = blockIdx.x*4 + (threadIdx.x >> 6);
  const int lane = threadIdx.x & 63;
  uint4 raw = *(const uint4*)(in + (long)row*512 + lane*8);
  const unsigned short* rs16 = (const unsigned short*)&raw;
  float v[8];
  #pragma unroll
  for (int c=0;c<8;++c) v[c] = bfu(rs16[c]);
  float sum = 0.f;
  #pragma unroll
  for (int c=0;c<8;++c) sum += v[c];
  #pragma unroll
  for (int msk=1; msk<64; msk<<=1) sum += __shfl_xor(sum, msk);
  float mu = sum * (1.f/512.f);
  float var = 0.f;
  #pragma unroll
  for (int c=0;c<8;++c){ v[c] -= mu; var += v[c]*v[c]; }
  #pragma unroll
  for (int msk=1; msk<64; msk<<=1) var += __shfl_xor(var, msk);
  float rs = rsqrtf(var*(1.f/512.f) + 1e-5f);
  float gv[8], bv[8];
  *(float4*)&gv[0] = *(const float4*)(g + lane*8);
  *(float4*)&gv[4] = *(const float4*)(g + lane*8 + 4);
  *(float4*)&bv[0] = *(const float4*)(bvec + lane*8);
  *(float4*)&bv[4] = *(const float4*)(bvec + lane*8 + 4);
  float y[8];
  #pragma unroll
  for (int c=0;c<8;++c) y[c] = v[c]*rs*gv[c] + bv[c];
  if (mode){
    float* dst = (float*)outp + (long)row*512 + lane*8;
    *(float4*)dst       = *(float4*)&y[0];
    *(float4*)(dst + 4) = *(float4*)&y[4];
  } else {
    uint4 out; unsigned short* os = (unsigned short*)&out;
    #pragma unroll
    for (int c=0;c<8;++c) os[c] = f2b(y[c]);
    *(uint4*)((unsigned short*)outp + (long)row*512 + lane*8) = out;
  }
}

// ---------------- out projection: u = t + relu(t @ Wo + bo), bf16 out ----------------
__global__ __launch_bounds__(256) void out_mfma(
    const unsigned short* t_bf, const unsigned short* Wt, const float* bo,
    unsigned short* u_bf)
{
  const int row0 = blockIdx.y*64, col0 = blockIdx.x*128;
  __shared__ unsigned short As[2][64][40];
  __shared__ unsigned short Ws[2][128][40];
  const int t = threadIdx.x;
  const int lane = t & 63, wid = t >> 6;
  const int ln = lane & 15, quad = lane >> 4;
  const int wy = wid >> 1, wx = wid & 1;   // wave: 32 rows x 64 cols
  f32x4 acc[2][4];
  #pragma unroll
  for (int i=0;i<2;++i){
    #pragma unroll
    for (int j=0;j<4;++j) acc[i][j] = (f32x4){0.f,0.f,0.f,0.f};
  }
  const int ar = t>>2, ac0 = (t&3)*8;
  const int wr = t>>1, wc0 = (t&1)*16;
  const unsigned short* Arow = t_bf + (long)(row0+ar)*512 + ac0;
  const unsigned short* Wrow = Wt   + (long)(col0+wr)*512 + wc0;
  uint4 a0 = *(const uint4*)(Arow);
  uint4 w0 = *(const uint4*)(Wrow);
  uint4 w1 = *(const uint4*)(Wrow + 8);
  *(uint4*)&As[0][ar][ac0] = a0;
  *(uint4*)&Ws[0][wr][wc0]   = w0;
  *(uint4*)&Ws[0][wr][wc0+8] = w1;
  __syncthreads();
  for (int it=0; it<16; ++it){
    const int cur = it & 1;
    if (it < 15){
      a0 = *(const uint4*)(Arow + (it+1)*32);
      w0 = *(const uint4*)(Wrow + (it+1)*32);
      w1 = *(const uint4*)(Wrow + (it+1)*32 + 8);
    }
    short8 a[2], b[4];
    #pragma unroll
    for (int mt=0;mt<2;++mt) a[mt] = *(const short8*)&As[cur][wy*32+mt*16+ln][quad*8];
    #pragma unroll
    for (int nt=0;nt<4;++nt) b[nt] = *(const short8*)&Ws[cur][wx*64+nt*16+ln][quad*8];
    #pragma unroll
    for (int mt=0;mt<2;++mt){
      #pragma unroll
      for (int nt=0;nt<4;++nt)
        acc[mt][nt] = __builtin_amdgcn_mfma_f32_16x16x32_bf16(a[mt], b[nt], acc[mt][nt], 0,0,0);
    }
    if (it < 15){
      *(uint4*)&As[cur^1][ar][ac0] = a0;
      *(uint4*)&Ws[cur^1][wr][wc0]   = w0;
      *(uint4*)&Ws[cur^1][wr][wc0+8] = w1;
    }
    __syncthreads();
  }
  float bias_v[4];
  #pragma unroll
  for (int nt=0;nt<4;++nt) bias_v[nt] = bo[col0 + wx*64 + nt*16 + ln];
  #pragma unroll
  for (int mt=0;mt<2;++mt){
    int row = row0 + wy*32 + mt*16 + quad*4;
    #pragma unroll
    for (int nt=0;nt<4;++nt){
      int col = col0 + wx*64 + nt*16 + ln;
      #pragma unroll
      for (int r=0;r<4;++r){
        long idx = (long)(row+r)*512 + col;
        float u = acc[mt][nt][r] + bias_v[nt];
        u = fmaxf(u, 0.f);
        u_bf[idx] = f2b(bfu(t_bf[idx]) + u);
      }
    }
  }
}

extern "C" void kernel_launch(void* const* d_in, const int* in_sizes, int n_in,
                              void* d_out, int out_size, void* d_ws, size_t ws_size,
                              hipStream_t stream)
{
  unsigned short* q_bf  = (unsigned short*)d_ws;
  unsigned short* k_bf  = q_bf  + 8192l*512;
  unsigned short* vt_bf = k_bf  + 8192l*512;
  unsigned short* t_bf  = vt_bf + 8192l*512;
  unsigned short* wt    = t_bf  + 8192l*512;
  unsigned short* qin   = wt + 4l*512*512;
  unsigned short* kin   = qin + 4194304;
  unsigned short* o_bf  = qin;   // alias: valid after proj_mfma
  unsigned short* u_bf  = kin;   // alias: valid after proj_mfma

  hipLaunchKernelGGL(prep_inputs, dim3(4352), dim3(256), 0, stream,
                     (const float*)d_in[5], (const float*)d_in[7],
                     (const float*)d_in[9], (const float*)d_in[11],
                     (const float*)d_in[0], (const float*)d_in[1], wt, qin);
  hipLaunchKernelGGL(proj_mfma, dim3(4,64,3), dim3(256), 0, stream,
                     qin, kin, wt,
                     (const float*)d_in[6], (const float*)d_in[8],
                     (const float*)d_in[10], q_bf, k_bf, vt_bf);
  hipLaunchKernelGGL(attn_mfma, dim3(64,8), dim3(256), 0, stream,
                     q_bf, k_bf, vt_bf,
                     (const float*)d_in[2], (const float*)d_in[3], o_bf);
  hipLaunchKernelGGL(ln_kernel, dim3(2048), dim3(256), 0, stream,
                     o_bf, (void*)t_bf, 0, (const float*)d_in[13], (const float*)d_in[14]);
  hipLaunchKernelGGL(out_mfma, dim3(4,128), dim3(256), 0, stream,
                     t_bf, wt + 3l*512*512, (const float*)d_in[12], u_bf);
  hipLaunchKernelGGL(ln_kernel, dim3(2048), dim3(256), 0, stream,
                     u_bf, d_out, 1, (const float*)d_in[15], (const float*)d_in[16]);
}

// Round 5
// 222.261 us; speedup vs baseline: 1.0891x; 1.0891x over previous
//
#include <hip/hip_runtime.h>

typedef __attribute__((ext_vector_type(8))) short short8;
typedef __attribute__((ext_vector_type(4))) float f32x4;

#define SCALE2 0.06375871571f   // (1/sqrt(512)) * log2(e)

__device__ __forceinline__ float bfu(unsigned short u){
  return __uint_as_float(((unsigned int)u) << 16);
}
__device__ __forceinline__ unsigned short f2b(float x){   // RNE
  unsigned int b = __float_as_uint(x);
  return (unsigned short)((b + 0x7fffu + ((b>>16)&1u)) >> 16);
}
// 8 contiguous f32 -> 8 bf16 packed in a uint4
__device__ __forceinline__ uint4 pack8(const float* f){
  float4 a = *(const float4*)f, b = *(const float4*)(f+4);
  uint4 r;
  r.x = (unsigned)f2b(a.x) | ((unsigned)f2b(a.y)<<16);
  r.y = (unsigned)f2b(a.z) | ((unsigned)f2b(a.w)<<16);
  r.z = (unsigned)f2b(b.x) | ((unsigned)f2b(b.y)<<16);
  r.w = (unsigned)f2b(b.z) | ((unsigned)f2b(b.w)<<16);
  return r;
}

// ---------------- fused input prep: weight transpose + q/k convert ----------------
__global__ __launch_bounds__(256) void prep_inputs(
    const float* Wq, const float* Wk, const float* Wv, const float* Wo,
    const float* q, const float* k, unsigned short* wt, unsigned short* qk_dst)
{
  const int id = blockIdx.x, t = threadIdx.x;
  if (id < 256){
    const int m = id >> 6;
    const float* W = (m==0)?Wq:(m==1)?Wk:(m==2)?Wv:Wo;
    unsigned short* dst = wt + (long)m*262144;
    __shared__ unsigned short tile[64][72];
    const int n0 = ((id>>3)&7)*64, k0 = (id&7)*64;
    {
      int r = t>>2, c0 = (t&3)*16;
      uint4 u0 = pack8(W + (long)(k0+r)*512 + n0 + c0);
      uint4 u1 = pack8(W + (long)(k0+r)*512 + n0 + c0 + 8);
      unsigned short* us0 = (unsigned short*)&u0;
      unsigned short* us1 = (unsigned short*)&u1;
      #pragma unroll
      for (int i=0;i<8;++i) tile[c0+i][r] = us0[i];
      #pragma unroll
      for (int i=0;i<8;++i) tile[c0+8+i][r] = us1[i];
    }
    __syncthreads();
    {
      int n = t>>2, ks = (t&3)*16;
      *(uint4*)(dst + (long)(n0+n)*512 + k0 + ks)     = *(uint4*)&tile[n][ks];
      *(uint4*)(dst + (long)(n0+n)*512 + k0 + ks + 8) = *(uint4*)&tile[n][ks+8];
    }
  } else {
    long i = ((long)(id-256)*256 + t)*8;
    const float* src = (i < 4194304) ? q + i : k + (i - 4194304);
    *(uint4*)(qk_dst + i) = pack8(src);
  }
}

// ---------------- QKV projection (bf16 MFMA, dbuf LDS, 1 barrier/iter) ----------------
__global__ __launch_bounds__(256) void proj_mfma(
    const unsigned short* qin, const unsigned short* kin, const unsigned short* wt,
    const float* bq, const float* bk, const float* bv,
    unsigned short* q_bf, unsigned short* k_bf, unsigned short* vt_bf)
{
  const int mat = blockIdx.z;
  const unsigned short* A = (mat==0)? qin : kin;
  const unsigned short* Wt = wt + (long)mat*262144;
  const float* bias = (mat==0)?bq:(mat==1)?bk:bv;
  const int row0 = blockIdx.y*128, col0 = blockIdx.x*128;
  __shared__ unsigned short As[2][128][40];
  __shared__ unsigned short Ws[2][128][40];
  const int t = threadIdx.x;
  const int lane = t & 63, wid = t >> 6;
  const int ln = lane & 15, quad = lane >> 4;
  const int wy = wid >> 1, wx = wid & 1;
  f32x4 acc[4][4];
  #pragma unroll
  for (int i=0;i<4;++i){
    #pragma unroll
    for (int j=0;j<4;++j) acc[i][j] = (f32x4){0.f,0.f,0.f,0.f};
  }
  const int sr = t>>1, sk0 = (t&1)*16;
  const unsigned short* Arow = A  + (long)(row0+sr)*512 + sk0;
  const unsigned short* Wrow = Wt + (long)(col0+sr)*512 + sk0;
  uint4 a0 = *(const uint4*)(Arow);
  uint4 a1 = *(const uint4*)(Arow + 8);
  uint4 w0 = *(const uint4*)(Wrow);
  uint4 w1 = *(const uint4*)(Wrow + 8);
  *(uint4*)&As[0][sr][sk0]   = a0;
  *(uint4*)&As[0][sr][sk0+8] = a1;
  *(uint4*)&Ws[0][sr][sk0]   = w0;
  *(uint4*)&Ws[0][sr][sk0+8] = w1;
  __syncthreads();
  for (int it=0; it<16; ++it){
    const int cur = it & 1;
    if (it < 15){
      a0 = *(const uint4*)(Arow + (it+1)*32);
      a1 = *(const uint4*)(Arow + (it+1)*32 + 8);
      w0 = *(const uint4*)(Wrow + (it+1)*32);
      w1 = *(const uint4*)(Wrow + (it+1)*32 + 8);
    }
    short8 a[4], b[4];
    #pragma unroll
    for (int mt=0;mt<4;++mt) a[mt] = *(const short8*)&As[cur][wy*64+mt*16+ln][quad*8];
    #pragma unroll
    for (int nt=0;nt<4;++nt) b[nt] = *(const short8*)&Ws[cur][wx*64+nt*16+ln][quad*8];
    #pragma unroll
    for (int mt=0;mt<4;++mt){
      #pragma unroll
      for (int nt=0;nt<4;++nt)
        acc[mt][nt] = __builtin_amdgcn_mfma_f32_16x16x32_bf16(a[mt], b[nt], acc[mt][nt], 0,0,0);
    }
    if (it < 15){
      *(uint4*)&As[cur^1][sr][sk0]   = a0;
      *(uint4*)&As[cur^1][sr][sk0+8] = a1;
      *(uint4*)&Ws[cur^1][sr][sk0]   = w0;
      *(uint4*)&Ws[cur^1][sr][sk0+8] = w1;
    }
    __syncthreads();
  }
  float bias_v[4];
  #pragma unroll
  for (int nt=0;nt<4;++nt) bias_v[nt] = bias[col0 + wx*64 + nt*16 + ln];
  if (mat < 2){
    unsigned short* dst = (mat==0)? q_bf : k_bf;
    #pragma unroll
    for (int mt=0;mt<4;++mt){
      int row = row0 + wy*64 + mt*16 + quad*4;
      #pragma unroll
      for (int nt=0;nt<4;++nt){
        int col = col0 + wx*64 + nt*16 + ln;
        #pragma unroll
        for (int r=0;r<4;++r)
          dst[(long)(row+r)*512 + col] = f2b(acc[mt][nt][r] + bias_v[nt]);
      }
    }
  } else {
    #pragma unroll
    for (int mt=0;mt<4;++mt){
      int row = row0 + wy*64 + mt*16 + quad*4;   // token base, 4-aligned
      int bb = row >> 10, sk = row & 1023;
      #pragma unroll
      for (int nt=0;nt<4;++nt){
        int col = col0 + wx*64 + nt*16 + ln;
        int h = col >> 6, dd = col & 63;
        uint2 pk2; unsigned short* pp = (unsigned short*)&pk2;
        #pragma unroll
        for (int r=0;r<4;++r) pp[r] = f2b(acc[mt][nt][r] + bias_v[nt]);
        *(uint2*)(vt_bf + (((long)((bb*8+h)*64+dd)) << 10) + sk) = pk2;
      }
    }
  }
}

// ---------------- flash attention: split-K across waves, staged 128-token tiles ----------------
// 8 waves/block, 128 q-rows/block. Wave (g = wid>>1, khalf = wid&1): q rows q0+g*32..+31
// (2 strips of 16, R0-amortization) x tokens khalf*512..+511 (its half of the keys).
// 8 super-iters stage a shared 128-token K/V tile (single-buffered, reg-prefetched T14);
// khalf halves consume disjoint 64-token sub-tiles. Softmax has no running max (scores
// presence-clamped), so split-K partials merge by pure addition of (oacc, lsum) at the end.
// All fragment patterns / paddings / Pw b64-write+b128-read mechanics are the R0/R3-verified ones.
__global__ __launch_bounds__(512, 4) void attn_mfma(
    const unsigned short* q_bf, const unsigned short* k_bf, const unsigned short* vt_bf,
    const float* pres_q, const float* pres_k, unsigned short* o_bf)
{
  const int bx = blockIdx.x;
  const int b = bx >> 3, h = bx & 7;
  const int q0 = blockIdx.y * 128;
  const int t = threadIdx.x;
  const int lane = t & 63, wid = t >> 6, ln = lane & 15, quad = lane >> 4;
  const int g = wid >> 1, khalf = wid & 1;

  __shared__ unsigned short Ks[128][72];    // [token][d]
  __shared__ unsigned short Vt[64][136];    // [d][token]
  __shared__ unsigned short Pw[8][16][72];  // wave-private P; reused as merge scratch
  __shared__ float pk_s[128];

  const unsigned short* Kg = k_bf  + ((long)b*1024)*512 + h*64;
  const unsigned short* Vg = vt_bf + (((long)(b*8+h)) << 16);
  const float* pkg = pres_k + b*1024;

  const int krow = t >> 2, kcol = (t & 3) * 16;   // 16 shorts per thread
  const int vrow = t >> 3, vcol = (t & 7) * 16;

  // prologue: stage tile 0
  {
    uint4 ka = *(const uint4*)(Kg + (long)krow*512 + kcol);
    uint4 kb = *(const uint4*)(Kg + (long)krow*512 + kcol + 8);
    uint4 va = *(const uint4*)(Vg + (long)vrow*1024 + vcol);
    uint4 vb = *(const uint4*)(Vg + (long)vrow*1024 + vcol + 8);
    *(uint4*)&Ks[krow][kcol]   = ka;
    *(uint4*)&Ks[krow][kcol+8] = kb;
    *(uint4*)&Vt[vrow][vcol]   = va;
    *(uint4*)&Vt[vrow][vcol+8] = vb;
    if (t < 128) pk_s[t] = pkg[t];
  }

  // Q fragments + presence (per strip)
  short8 aq[2][2]; float av[2], mval[2];
  #pragma unroll
  for (int st=0;st<2;++st){
    int qi = q0 + g*32 + st*16 + ln;
    const unsigned short* qrow = q_bf + ((long)(b*1024 + qi))*512 + h*64;
    aq[st][0] = *(const short8*)(qrow + quad*8);
    aq[st][1] = *(const short8*)(qrow + 32 + quad*8);
    av[st]   = SCALE2 * pres_q[b*1024 + qi];
    mval[st] = (av[st] == 0.f) ? 0.f : -43.f;
  }
  f32x4 oacc[2][4];
  #pragma unroll
  for (int st=0;st<2;++st){
    #pragma unroll
    for (int i=0;i<4;++i) oacc[st][i] = (f32x4){0.f,0.f,0.f,0.f};
  }
  float lsum[2] = {0.f, 0.f};
  __syncthreads();

  const int tb = khalf * 64;   // this wave's token base within the staged tile
  for (int s=0; s<8; ++s){
    // reg-prefetch next tile (issued before compute; lands under it)
    uint4 pka, pkb, pva, pvb; float ppk = 0.f;
    if (s < 7){
      const long off = (long)(s+1)*128;
      pka = *(const uint4*)(Kg + (off + krow)*512 + kcol);
      pkb = *(const uint4*)(Kg + (off + krow)*512 + kcol + 8);
      pva = *(const uint4*)(Vg + (long)vrow*1024 + off + vcol);
      pvb = *(const uint4*)(Vg + (long)vrow*1024 + off + vcol + 8);
      if (t < 128) ppk = pkg[off + t];
    }
    #pragma unroll
    for (int st=0; st<2; ++st){
      // S^T = K Q^T : lane holds S[k = tb+kt*16+quad*4+r][q = ln]
      f32x4 sc[4];
      #pragma unroll
      for (int kt=0;kt<4;++kt) sc[kt] = (f32x4){0.f,0.f,0.f,0.f};
      __builtin_amdgcn_s_setprio(1);
      #pragma unroll
      for (int kt=0;kt<4;++kt){
        short8 kb0 = *(const short8*)&Ks[tb + kt*16+ln][quad*8];
        short8 kb1 = *(const short8*)&Ks[tb + kt*16+ln][32+quad*8];
        sc[kt] = __builtin_amdgcn_mfma_f32_16x16x32_bf16(kb0, aq[st][0], sc[kt], 0,0,0);
        sc[kt] = __builtin_amdgcn_mfma_f32_16x16x32_bf16(kb1, aq[st][1], sc[kt], 0,0,0);
      }
      __builtin_amdgcn_s_setprio(0);
      // softmax + vectorized P write (true k columns)
      #pragma unroll
      for (int kt=0;kt<4;++kt){
        float4 pk4 = *(const float4*)&pk_s[tb + kt*16 + quad*4];
        float x0 = __builtin_fmaf(pk4.x, __builtin_fmaf(sc[kt][0], av[st], -mval[st]), mval[st]);
        float x1 = __builtin_fmaf(pk4.y, __builtin_fmaf(sc[kt][1], av[st], -mval[st]), mval[st]);
        float x2 = __builtin_fmaf(pk4.z, __builtin_fmaf(sc[kt][2], av[st], -mval[st]), mval[st]);
        float x3 = __builtin_fmaf(pk4.w, __builtin_fmaf(sc[kt][3], av[st], -mval[st]), mval[st]);
        float e0 = __builtin_amdgcn_exp2f(x0);
        float e1 = __builtin_amdgcn_exp2f(x1);
        float e2 = __builtin_amdgcn_exp2f(x2);
        float e3 = __builtin_amdgcn_exp2f(x3);
        lsum[st] += (e0+e1)+(e2+e3);
        uint2 w;
        w.x = (unsigned)f2b(e0) | ((unsigned)f2b(e1)<<16);
        w.y = (unsigned)f2b(e2) | ((unsigned)f2b(e3)<<16);
        *(uint2*)&Pw[wid][ln][kt*16 + quad*4] = w;
      }
      // O += P V
      short8 ap0 = *(const short8*)&Pw[wid][ln][quad*8];
      short8 ap1 = *(const short8*)&Pw[wid][ln][32 + quad*8];
      __builtin_amdgcn_s_setprio(1);
      #pragma unroll
      for (int dt=0;dt<4;++dt){
        short8 vb0 = *(const short8*)&Vt[dt*16+ln][tb + quad*8];
        short8 vb1 = *(const short8*)&Vt[dt*16+ln][tb + 32 + quad*8];
        oacc[st][dt] = __builtin_amdgcn_mfma_f32_16x16x32_bf16(ap0, vb0, oacc[st][dt], 0,0,0);
        oacc[st][dt] = __builtin_amdgcn_mfma_f32_16x16x32_bf16(ap1, vb1, oacc[st][dt], 0,0,0);
      }
      __builtin_amdgcn_s_setprio(0);
    }
    __syncthreads();   // all waves done reading tile s
    if (s < 7){
      *(uint4*)&Ks[krow][kcol]   = pka;
      *(uint4*)&Ks[krow][kcol+8] = pkb;
      *(uint4*)&Vt[vrow][vcol]   = pva;
      *(uint4*)&Vt[vrow][vcol+8] = pvb;
      if (t < 128) pk_s[t] = ppk;
      __syncthreads(); // tile s+1 visible
    }
  }

  // split-K merge (pure addition; no max-rescale in this softmax) + epilogue
  float* MSf = (float*)&Pw[0][0][0];           // [4][64][18] floats overlays Pw
  #pragma unroll
  for (int st=0; st<2; ++st){
    __syncthreads();
    if (khalf == 1){
      float* m = MSf + (g*64 + lane)*18;
      #pragma unroll
      for (int dt=0;dt<4;++dt){
        #pragma unroll
        for (int r=0;r<4;++r) m[dt*4+r] = oacc[st][dt][r];
      }
      m[16] = lsum[st];
    }
    __syncthreads();
    if (khalf == 0){
      const float* m = MSf + (g*64 + lane)*18;
      float l = lsum[st] + m[16];
      #pragma unroll
      for (int dt=0;dt<4;++dt){
        #pragma unroll
        for (int r=0;r<4;++r) oacc[st][dt][r] += m[dt*4+r];
      }
      l += __shfl_xor(l, 16);
      l += __shfl_xor(l, 32);
      #pragma unroll
      for (int r=0;r<4;++r){
        float lr = __shfl(l, quad*4 + r);
        float inv = 1.f / lr;
        int ql = q0 + g*32 + st*16 + quad*4 + r;
        long base = ((long)(b*1024 + ql))*512 + h*64;
        #pragma unroll
        for (int dt=0;dt<4;++dt){
          float qh = bfu(q_bf[base + dt*16 + ln]);
          o_bf[base + dt*16 + ln] = f2b(qh + oacc[st][dt][r]*inv);
        }
      }
    }
  }
}

// ---------------- layernorm (wave per row), bf16 input ----------------
__global__ __launch_bounds__(256) void ln_kernel(
    const unsigned short* in, void* outp, int mode, const float* g, const float* bvec)
{
  const int row = blockIdx.x*4 + (threadIdx.x >> 6);
  const int lane = threadIdx.x & 63;
  uint4 raw = *(const uint4*)(in + (long)row*512 + lane*8);
  const unsigned short* rs16 = (const unsigned short*)&raw;
  float v[8];
  #pragma unroll
  for (int c=0;c<8;++c) v[c] = bfu(rs16[c]);
  float sum = 0.f;
  #pragma unroll
  for (int c=0;c<8;++c) sum += v[c];
  #pragma unroll
  for (int msk=1; msk<64; msk<<=1) sum += __shfl_xor(sum, msk);
  float mu = sum * (1.f/512.f);
  float var = 0.f;
  #pragma unroll
  for (int c=0;c<8;++c){ v[c] -= mu; var += v[c]*v[c]; }
  #pragma unroll
  for (int msk=1; msk<64; msk<<=1) var += __shfl_xor(var, msk);
  float rs = rsqrtf(var*(1.f/512.f) + 1e-5f);
  float gv[8], bv[8];
  *(float4*)&gv[0] = *(const float4*)(g + lane*8);
  *(float4*)&gv[4] = *(const float4*)(g + lane*8 + 4);
  *(float4*)&bv[0] = *(const float4*)(bvec + lane*8);
  *(float4*)&bv[4] = *(const float4*)(bvec + lane*8 + 4);
  float y[8];
  #pragma unroll
  for (int c=0;c<8;++c) y[c] = v[c]*rs*gv[c] + bv[c];
  if (mode){
    float* dst = (float*)outp + (long)row*512 + lane*8;
    *(float4*)dst       = *(float4*)&y[0];
    *(float4*)(dst + 4) = *(float4*)&y[4];
  } else {
    uint4 out; unsigned short* os = (unsigned short*)&out;
    #pragma unroll
    for (int c=0;c<8;++c) os[c] = f2b(y[c]);
    *(uint4*)((unsigned short*)outp + (long)row*512 + lane*8) = out;
  }
}

// ---------------- out projection: u = t + relu(t @ Wo + bo), bf16 out ----------------
__global__ __launch_bounds__(256) void out_mfma(
    const unsigned short* t_bf, const unsigned short* Wt, const float* bo,
    unsigned short* u_bf)
{
  const int row0 = blockIdx.y*64, col0 = blockIdx.x*128;
  __shared__ unsigned short As[2][64][40];
  __shared__ unsigned short Ws[2][128][40];
  const int t = threadIdx.x;
  const int lane = t & 63, wid = t >> 6;
  const int ln = lane & 15, quad = lane >> 4;
  const int wy = wid >> 1, wx = wid & 1;   // wave: 32 rows x 64 cols
  f32x4 acc[2][4];
  #pragma unroll
  for (int i=0;i<2;++i){
    #pragma unroll
    for (int j=0;j<4;++j) acc[i][j] = (f32x4){0.f,0.f,0.f,0.f};
  }
  const int ar = t>>2, ac0 = (t&3)*8;
  const int wr = t>>1, wc0 = (t&1)*16;
  const unsigned short* Arow = t_bf + (long)(row0+ar)*512 + ac0;
  const unsigned short* Wrow = Wt   + (long)(col0+wr)*512 + wc0;
  uint4 a0 = *(const uint4*)(Arow);
  uint4 w0 = *(const uint4*)(Wrow);
  uint4 w1 = *(const uint4*)(Wrow + 8);
  *(uint4*)&As[0][ar][ac0] = a0;
  *(uint4*)&Ws[0][wr][wc0]   = w0;
  *(uint4*)&Ws[0][wr][wc0+8] = w1;
  __syncthreads();
  for (int it=0; it<16; ++it){
    const int cur = it & 1;
    if (it < 15){
      a0 = *(const uint4*)(Arow + (it+1)*32);
      w0 = *(const uint4*)(Wrow + (it+1)*32);
      w1 = *(const uint4*)(Wrow + (it+1)*32 + 8);
    }
    short8 a[2], b[4];
    #pragma unroll
    for (int mt=0;mt<2;++mt) a[mt] = *(const short8*)&As[cur][wy*32+mt*16+ln][quad*8];
    #pragma unroll
    for (int nt=0;nt<4;++nt) b[nt] = *(const short8*)&Ws[cur][wx*64+nt*16+ln][quad*8];
    #pragma unroll
    for (int mt=0;mt<2;++mt){
      #pragma unroll
      for (int nt=0;nt<4;++nt)
        acc[mt][nt] = __builtin_amdgcn_mfma_f32_16x16x32_bf16(a[mt], b[nt], acc[mt][nt], 0,0,0);
    }
    if (it < 15){
      *(uint4*)&As[cur^1][ar][ac0] = a0;
      *(uint4*)&Ws[cur^1][wr][wc0]   = w0;
      *(uint4*)&Ws[cur^1][wr][wc0+8] = w1;
    }
    __syncthreads();
  }
  float bias_v[4];
  #pragma unroll
  for (int nt=0;nt<4;++nt) bias_v[nt] = bo[col0 + wx*64 + nt*16 + ln];
  #pragma unroll
  for (int mt=0;mt<2;++mt){
    int row = row0 + wy*32 + mt*16 + quad*4;
    #pragma unroll
    for (int nt=0;nt<4;++nt){
      int col = col0 + wx*64 + nt*16 + ln;
      #pragma unroll
      for (int r=0;r<4;++r){
        long idx = (long)(row+r)*512 + col;
        float u = acc[mt][nt][r] + bias_v[nt];
        u = fmaxf(u, 0.f);
        u_bf[idx] = f2b(bfu(t_bf[idx]) + u);
      }
    }
  }
}

extern "C" void kernel_launch(void* const* d_in, const int* in_sizes, int n_in,
                              void* d_out, int out_size, void* d_ws, size_t ws_size,
                              hipStream_t stream)
{
  unsigned short* q_bf  = (unsigned short*)d_ws;
  unsigned short* k_bf  = q_bf  + 8192l*512;
  unsigned short* vt_bf = k_bf  + 8192l*512;
  unsigned short* t_bf  = vt_bf + 8192l*512;
  unsigned short* wt    = t_bf  + 8192l*512;
  unsigned short* qin   = wt + 4l*512*512;
  unsigned short* kin   = qin + 4194304;
  unsigned short* o_bf  = qin;   // alias: valid after proj_mfma
  unsigned short* u_bf  = kin;   // alias: valid after proj_mfma

  hipLaunchKernelGGL(prep_inputs, dim3(4352), dim3(256), 0, stream,
                     (const float*)d_in[5], (const float*)d_in[7],
                     (const float*)d_in[9], (const float*)d_in[11],
                     (const float*)d_in[0], (const float*)d_in[1], wt, qin);
  hipLaunchKernelGGL(proj_mfma, dim3(4,64,3), dim3(256), 0, stream,
                     qin, kin, wt,
                     (const float*)d_in[6], (const float*)d_in[8],
                     (const float*)d_in[10], q_bf, k_bf, vt_bf);
  hipLaunchKernelGGL(attn_mfma, dim3(64,8), dim3(512), 0, stream,
                     q_bf, k_bf, vt_bf,
                     (const float*)d_in[2], (const float*)d_in[3], o_bf);
  hipLaunchKernelGGL(ln_kernel, dim3(2048), dim3(256), 0, stream,
                     o_bf, (void*)t_bf, 0, (const float*)d_in[13], (const float*)d_in[14]);
  hipLaunchKernelGGL(out_mfma, dim3(4,128), dim3(256), 0, stream,
                     t_bf, wt + 3l*512*512, (const float*)d_in[12], u_bf);
  hipLaunchKernelGGL(ln_kernel, dim3(2048), dim3(256), 0, stream,
                     u_bf, d_out, 1, (const float*)d_in[15], (const float*)d_in[16]);
}

// Round 6
// 216.711 us; speedup vs baseline: 1.1170x; 1.0256x over previous
//
#include <hip/hip_runtime.h>

typedef __attribute__((ext_vector_type(8))) short short8;
typedef __attribute__((ext_vector_type(4))) float f32x4;

#define SCALE2 0.06375871571f   // (1/sqrt(512)) * log2(e)

__device__ __forceinline__ float bfu(unsigned short u){
  return __uint_as_float(((unsigned int)u) << 16);
}
__device__ __forceinline__ unsigned short f2b(float x){   // RNE
  unsigned int b = __float_as_uint(x);
  return (unsigned short)((b + 0x7fffu + ((b>>16)&1u)) >> 16);
}
// 8 contiguous f32 -> 8 bf16 packed in a uint4
__device__ __forceinline__ uint4 pack8(const float* f){
  float4 a = *(const float4*)f, b = *(const float4*)(f+4);
  uint4 r;
  r.x = (unsigned)f2b(a.x) | ((unsigned)f2b(a.y)<<16);
  r.y = (unsigned)f2b(a.z) | ((unsigned)f2b(a.w)<<16);
  r.z = (unsigned)f2b(b.x) | ((unsigned)f2b(b.y)<<16);
  r.w = (unsigned)f2b(b.z) | ((unsigned)f2b(b.w)<<16);
  return r;
}

// ---------------- fused input prep: weight transpose + q/k convert ----------------
__global__ __launch_bounds__(256) void prep_inputs(
    const float* Wq, const float* Wk, const float* Wv, const float* Wo,
    const float* q, const float* k, unsigned short* wt, unsigned short* qk_dst)
{
  const int id = blockIdx.x, t = threadIdx.x;
  if (id < 256){
    const int m = id >> 6;
    const float* W = (m==0)?Wq:(m==1)?Wk:(m==2)?Wv:Wo;
    unsigned short* dst = wt + (long)m*262144;
    __shared__ unsigned short tile[64][72];
    const int n0 = ((id>>3)&7)*64, k0 = (id&7)*64;
    {
      int r = t>>2, c0 = (t&3)*16;
      uint4 u0 = pack8(W + (long)(k0+r)*512 + n0 + c0);
      uint4 u1 = pack8(W + (long)(k0+r)*512 + n0 + c0 + 8);
      unsigned short* us0 = (unsigned short*)&u0;
      unsigned short* us1 = (unsigned short*)&u1;
      #pragma unroll
      for (int i=0;i<8;++i) tile[c0+i][r] = us0[i];
      #pragma unroll
      for (int i=0;i<8;++i) tile[c0+8+i][r] = us1[i];
    }
    __syncthreads();
    {
      int n = t>>2, ks = (t&3)*16;
      *(uint4*)(dst + (long)(n0+n)*512 + k0 + ks)     = *(uint4*)&tile[n][ks];
      *(uint4*)(dst + (long)(n0+n)*512 + k0 + ks + 8) = *(uint4*)&tile[n][ks+8];
    }
  } else {
    long i = ((long)(id-256)*256 + t)*8;
    const float* src = (i < 4194304) ? q + i : k + (i - 4194304);
    *(uint4*)(qk_dst + i) = pack8(src);
  }
}

// ---------------- QKV projection (bf16 MFMA, dbuf LDS, 1 barrier/iter) ----------------
__global__ __launch_bounds__(256) void proj_mfma(
    const unsigned short* qin, const unsigned short* kin, const unsigned short* wt,
    const float* bq, const float* bk, const float* bv,
    unsigned short* q_bf, unsigned short* k_bf, unsigned short* vt_bf)
{
  const int mat = blockIdx.z;
  const unsigned short* A = (mat==0)? qin : kin;
  const unsigned short* Wt = wt + (long)mat*262144;
  const float* bias = (mat==0)?bq:(mat==1)?bk:bv;
  const int row0 = blockIdx.y*128, col0 = blockIdx.x*128;
  __shared__ unsigned short As[2][128][40];
  __shared__ unsigned short Ws[2][128][40];
  const int t = threadIdx.x;
  const int lane = t & 63, wid = t >> 6;
  const int ln = lane & 15, quad = lane >> 4;
  const int wy = wid >> 1, wx = wid & 1;
  f32x4 acc[4][4];
  #pragma unroll
  for (int i=0;i<4;++i){
    #pragma unroll
    for (int j=0;j<4;++j) acc[i][j] = (f32x4){0.f,0.f,0.f,0.f};
  }
  const int sr = t>>1, sk0 = (t&1)*16;
  const unsigned short* Arow = A  + (long)(row0+sr)*512 + sk0;
  const unsigned short* Wrow = Wt + (long)(col0+sr)*512 + sk0;
  uint4 a0 = *(const uint4*)(Arow);
  uint4 a1 = *(const uint4*)(Arow + 8);
  uint4 w0 = *(const uint4*)(Wrow);
  uint4 w1 = *(const uint4*)(Wrow + 8);
  *(uint4*)&As[0][sr][sk0]   = a0;
  *(uint4*)&As[0][sr][sk0+8] = a1;
  *(uint4*)&Ws[0][sr][sk0]   = w0;
  *(uint4*)&Ws[0][sr][sk0+8] = w1;
  __syncthreads();
  for (int it=0; it<16; ++it){
    const int cur = it & 1;
    if (it < 15){
      a0 = *(const uint4*)(Arow + (it+1)*32);
      a1 = *(const uint4*)(Arow + (it+1)*32 + 8);
      w0 = *(const uint4*)(Wrow + (it+1)*32);
      w1 = *(const uint4*)(Wrow + (it+1)*32 + 8);
    }
    short8 a[4], b[4];
    #pragma unroll
    for (int mt=0;mt<4;++mt) a[mt] = *(const short8*)&As[cur][wy*64+mt*16+ln][quad*8];
    #pragma unroll
    for (int nt=0;nt<4;++nt) b[nt] = *(const short8*)&Ws[cur][wx*64+nt*16+ln][quad*8];
    #pragma unroll
    for (int mt=0;mt<4;++mt){
      #pragma unroll
      for (int nt=0;nt<4;++nt)
        acc[mt][nt] = __builtin_amdgcn_mfma_f32_16x16x32_bf16(a[mt], b[nt], acc[mt][nt], 0,0,0);
    }
    if (it < 15){
      *(uint4*)&As[cur^1][sr][sk0]   = a0;
      *(uint4*)&As[cur^1][sr][sk0+8] = a1;
      *(uint4*)&Ws[cur^1][sr][sk0]   = w0;
      *(uint4*)&Ws[cur^1][sr][sk0+8] = w1;
    }
    __syncthreads();
  }
  float bias_v[4];
  #pragma unroll
  for (int nt=0;nt<4;++nt) bias_v[nt] = bias[col0 + wx*64 + nt*16 + ln];
  if (mat < 2){
    unsigned short* dst = (mat==0)? q_bf : k_bf;
    #pragma unroll
    for (int mt=0;mt<4;++mt){
      int row = row0 + wy*64 + mt*16 + quad*4;
      #pragma unroll
      for (int nt=0;nt<4;++nt){
        int col = col0 + wx*64 + nt*16 + ln;
        #pragma unroll
        for (int r=0;r<4;++r)
          dst[(long)(row+r)*512 + col] = f2b(acc[mt][nt][r] + bias_v[nt]);
      }
    }
  } else {
    #pragma unroll
    for (int mt=0;mt<4;++mt){
      int row = row0 + wy*64 + mt*16 + quad*4;   // token base, 4-aligned
      int bb = row >> 10, sk = row & 1023;
      #pragma unroll
      for (int nt=0;nt<4;++nt){
        int col = col0 + wx*64 + nt*16 + ln;
        int h = col >> 6, dd = col & 63;
        uint2 pk2; unsigned short* pp = (unsigned short*)&pk2;
        #pragma unroll
        for (int r=0;r<4;++r) pp[r] = f2b(acc[mt][nt][r] + bias_v[nt]);
        *(uint2*)(vt_bf + (((long)((bb*8+h)*64+dd)) << 10) + sk) = pk2;
      }
    }
  }
}

// ---------------- flash attention: split-K across waves, strip-amortized fragments ----------------
// 8 waves/block (512 thr), 128 q-rows/block. Wave (g = wid>>1, khalf = wid&1): 32 q-rows
// (2 strips of 16) x its half of the keys. 8 super-iters stage a shared 128-token K/V tile
// (single-buffered, reg-prefetched); khalf halves consume disjoint 64-token sub-tiles.
// K/V FRAGMENT READS ARE AMORTIZED ACROSS BOTH STRIPS (each kb/vb feeds 2 strips' MFMAs,
// the R0-verified property). Pw holds both strips (32 rows/wave). No-max softmax ->
// split-K partials merge by pure addition. launch_bounds (512,2) so VGPRs float to need
// (~110) instead of being capped at 64 (R5's spill disaster: WRITE_SIZE 54MB of scratch).
__global__ __launch_bounds__(512, 2) void attn_mfma(
    const unsigned short* q_bf, const unsigned short* k_bf, const unsigned short* vt_bf,
    const float* pres_q, const float* pres_k, unsigned short* o_bf)
{
  const int bx = blockIdx.x;
  const int b = bx >> 3, h = bx & 7;
  const int q0 = blockIdx.y * 128;
  const int t = threadIdx.x;
  const int lane = t & 63, wid = t >> 6, ln = lane & 15, quad = lane >> 4;
  const int g = wid >> 1, khalf = wid & 1;

  __shared__ unsigned short Ks[128][72];    // [token][d]
  __shared__ unsigned short Vt[64][136];    // [d][token]
  __shared__ unsigned short Pw[8][32][72];  // wave-private P (both strips); merge scratch overlay
  __shared__ float pk_s[128];

  const unsigned short* Kg = k_bf  + ((long)b*1024)*512 + h*64;
  const unsigned short* Vg = vt_bf + (((long)(b*8+h)) << 16);
  const float* pkg = pres_k + b*1024;

  const int krow = t >> 2, kcol = (t & 3) * 16;   // 16 shorts per thread
  const int vrow = t >> 3, vcol = (t & 7) * 16;

  // prologue: stage tile 0
  {
    uint4 ka = *(const uint4*)(Kg + (long)krow*512 + kcol);
    uint4 kb = *(const uint4*)(Kg + (long)krow*512 + kcol + 8);
    uint4 va = *(const uint4*)(Vg + (long)vrow*1024 + vcol);
    uint4 vb = *(const uint4*)(Vg + (long)vrow*1024 + vcol + 8);
    *(uint4*)&Ks[krow][kcol]   = ka;
    *(uint4*)&Ks[krow][kcol+8] = kb;
    *(uint4*)&Vt[vrow][vcol]   = va;
    *(uint4*)&Vt[vrow][vcol+8] = vb;
    if (t < 128) pk_s[t] = pkg[t];
  }

  // Q fragments + presence (per strip)
  short8 aq[2][2]; float av[2], mval[2];
  #pragma unroll
  for (int st=0;st<2;++st){
    int qi = q0 + g*32 + st*16 + ln;
    const unsigned short* qrow = q_bf + ((long)(b*1024 + qi))*512 + h*64;
    aq[st][0] = *(const short8*)(qrow + quad*8);
    aq[st][1] = *(const short8*)(qrow + 32 + quad*8);
    av[st]   = SCALE2 * pres_q[b*1024 + qi];
    mval[st] = (av[st] == 0.f) ? 0.f : -43.f;
  }
  f32x4 oacc[2][4];
  #pragma unroll
  for (int st=0;st<2;++st){
    #pragma unroll
    for (int i=0;i<4;++i) oacc[st][i] = (f32x4){0.f,0.f,0.f,0.f};
  }
  float lsum[2] = {0.f, 0.f};
  __syncthreads();

  const int tb = khalf * 64;   // this wave's token base within the staged tile
  for (int s=0; s<8; ++s){
    // reg-prefetch next tile (issued before compute; lands under it)
    uint4 pka, pkb, pva, pvb; float ppk = 0.f;
    if (s < 7){
      const long off = (long)(s+1)*128;
      pka = *(const uint4*)(Kg + (off + krow)*512 + kcol);
      pkb = *(const uint4*)(Kg + (off + krow)*512 + kcol + 8);
      pva = *(const uint4*)(Vg + (long)vrow*1024 + off + vcol);
      pvb = *(const uint4*)(Vg + (long)vrow*1024 + off + vcol + 8);
      if (t < 128) ppk = pkg[off + t];
    }
    // S^T = K Q^T for BOTH strips; each kb fragment pair feeds both
    f32x4 sc[2][4];
    #pragma unroll
    for (int st=0;st<2;++st){
      #pragma unroll
      for (int kt=0;kt<4;++kt) sc[st][kt] = (f32x4){0.f,0.f,0.f,0.f};
    }
    __builtin_amdgcn_s_setprio(1);
    #pragma unroll
    for (int kt=0;kt<4;++kt){
      short8 kb0 = *(const short8*)&Ks[tb + kt*16+ln][quad*8];
      short8 kb1 = *(const short8*)&Ks[tb + kt*16+ln][32+quad*8];
      sc[0][kt] = __builtin_amdgcn_mfma_f32_16x16x32_bf16(kb0, aq[0][0], sc[0][kt], 0,0,0);
      sc[0][kt] = __builtin_amdgcn_mfma_f32_16x16x32_bf16(kb1, aq[0][1], sc[0][kt], 0,0,0);
      sc[1][kt] = __builtin_amdgcn_mfma_f32_16x16x32_bf16(kb0, aq[1][0], sc[1][kt], 0,0,0);
      sc[1][kt] = __builtin_amdgcn_mfma_f32_16x16x32_bf16(kb1, aq[1][1], sc[1][kt], 0,0,0);
    }
    __builtin_amdgcn_s_setprio(0);
    // softmax + vectorized P write (true k columns), both strips
    #pragma unroll
    for (int st=0;st<2;++st){
      #pragma unroll
      for (int kt=0;kt<4;++kt){
        float4 pk4 = *(const float4*)&pk_s[tb + kt*16 + quad*4];
        float x0 = __builtin_fmaf(pk4.x, __builtin_fmaf(sc[st][kt][0], av[st], -mval[st]), mval[st]);
        float x1 = __builtin_fmaf(pk4.y, __builtin_fmaf(sc[st][kt][1], av[st], -mval[st]), mval[st]);
        float x2 = __builtin_fmaf(pk4.z, __builtin_fmaf(sc[st][kt][2], av[st], -mval[st]), mval[st]);
        float x3 = __builtin_fmaf(pk4.w, __builtin_fmaf(sc[st][kt][3], av[st], -mval[st]), mval[st]);
        float e0 = __builtin_amdgcn_exp2f(x0);
        float e1 = __builtin_amdgcn_exp2f(x1);
        float e2 = __builtin_amdgcn_exp2f(x2);
        float e3 = __builtin_amdgcn_exp2f(x3);
        lsum[st] += (e0+e1)+(e2+e3);
        uint2 w;
        w.x = (unsigned)f2b(e0) | ((unsigned)f2b(e1)<<16);
        w.y = (unsigned)f2b(e2) | ((unsigned)f2b(e3)<<16);
        *(uint2*)&Pw[wid][st*16+ln][kt*16 + quad*4] = w;
      }
    }
    // O += P V for BOTH strips; each vb fragment pair feeds both
    short8 ap[2][2];
    #pragma unroll
    for (int st=0;st<2;++st){
      ap[st][0] = *(const short8*)&Pw[wid][st*16+ln][quad*8];
      ap[st][1] = *(const short8*)&Pw[wid][st*16+ln][32 + quad*8];
    }
    __builtin_amdgcn_s_setprio(1);
    #pragma unroll
    for (int dt=0;dt<4;++dt){
      short8 vb0 = *(const short8*)&Vt[dt*16+ln][tb + quad*8];
      short8 vb1 = *(const short8*)&Vt[dt*16+ln][tb + 32 + quad*8];
      oacc[0][dt] = __builtin_amdgcn_mfma_f32_16x16x32_bf16(ap[0][0], vb0, oacc[0][dt], 0,0,0);
      oacc[0][dt] = __builtin_amdgcn_mfma_f32_16x16x32_bf16(ap[0][1], vb1, oacc[0][dt], 0,0,0);
      oacc[1][dt] = __builtin_amdgcn_mfma_f32_16x16x32_bf16(ap[1][0], vb0, oacc[1][dt], 0,0,0);
      oacc[1][dt] = __builtin_amdgcn_mfma_f32_16x16x32_bf16(ap[1][1], vb1, oacc[1][dt], 0,0,0);
    }
    __builtin_amdgcn_s_setprio(0);
    __syncthreads();   // all waves done reading tile s
    if (s < 7){
      *(uint4*)&Ks[krow][kcol]   = pka;
      *(uint4*)&Ks[krow][kcol+8] = pkb;
      *(uint4*)&Vt[vrow][vcol]   = pva;
      *(uint4*)&Vt[vrow][vcol+8] = pvb;
      if (t < 128) pk_s[t] = ppk;
      __syncthreads(); // tile s+1 visible
    }
  }

  // split-K merge (pure addition; no max-rescale in this softmax) + epilogue
  float* MSf = (float*)&Pw[0][0][0];           // [4][64][18] floats overlays Pw
  #pragma unroll
  for (int st=0; st<2; ++st){
    __syncthreads();
    if (khalf == 1){
      float* m = MSf + (g*64 + lane)*18;
      #pragma unroll
      for (int dt=0;dt<4;++dt){
        #pragma unroll
        for (int r=0;r<4;++r) m[dt*4+r] = oacc[st][dt][r];
      }
      m[16] = lsum[st];
    }
    __syncthreads();
    if (khalf == 0){
      const float* m = MSf + (g*64 + lane)*18;
      float l = lsum[st] + m[16];
      #pragma unroll
      for (int dt=0;dt<4;++dt){
        #pragma unroll
        for (int r=0;r<4;++r) oacc[st][dt][r] += m[dt*4+r];
      }
      l += __shfl_xor(l, 16);
      l += __shfl_xor(l, 32);
      #pragma unroll
      for (int r=0;r<4;++r){
        float lr = __shfl(l, quad*4 + r);
        float inv = 1.f / lr;
        int ql = q0 + g*32 + st*16 + quad*4 + r;
        long base = ((long)(b*1024 + ql))*512 + h*64;
        #pragma unroll
        for (int dt=0;dt<4;++dt){
          float qh = bfu(q_bf[base + dt*16 + ln]);
          o_bf[base + dt*16 + ln] = f2b(qh + oacc[st][dt][r]*inv);
        }
      }
    }
  }
}

// ---------------- layernorm (wave per row), bf16 input ----------------
__global__ __launch_bounds__(256) void ln_kernel(
    const unsigned short* in, void* outp, int mode, const float* g, const float* bvec)
{
  const int row = blockIdx.x*4 + (threadIdx.x >> 6);
  const int lane = threadIdx.x & 63;
  uint4 raw = *(const uint4*)(in + (long)row*512 + lane*8);
  const unsigned short* rs16 = (const unsigned short*)&raw;
  float v[8];
  #pragma unroll
  for (int c=0;c<8;++c) v[c] = bfu(rs16[c]);
  float sum = 0.f;
  #pragma unroll
  for (int c=0;c<8;++c) sum += v[c];
  #pragma unroll
  for (int msk=1; msk<64; msk<<=1) sum += __shfl_xor(sum, msk);
  float mu = sum * (1.f/512.f);
  float var = 0.f;
  #pragma unroll
  for (int c=0;c<8;++c){ v[c] -= mu; var += v[c]*v[c]; }
  #pragma unroll
  for (int msk=1; msk<64; msk<<=1) var += __shfl_xor(var, msk);
  float rs = rsqrtf(var*(1.f/512.f) + 1e-5f);
  float gv[8], bv[8];
  *(float4*)&gv[0] = *(const float4*)(g + lane*8);
  *(float4*)&gv[4] = *(const float4*)(g + lane*8 + 4);
  *(float4*)&bv[0] = *(const float4*)(bvec + lane*8);
  *(float4*)&bv[4] = *(const float4*)(bvec + lane*8 + 4);
  float y[8];
  #pragma unroll
  for (int c=0;c<8;++c) y[c] = v[c]*rs*gv[c] + bv[c];
  if (mode){
    float* dst = (float*)outp + (long)row*512 + lane*8;
    *(float4*)dst       = *(float4*)&y[0];
    *(float4*)(dst + 4) = *(float4*)&y[4];
  } else {
    uint4 out; unsigned short* os = (unsigned short*)&out;
    #pragma unroll
    for (int c=0;c<8;++c) os[c] = f2b(y[c]);
    *(uint4*)((unsigned short*)outp + (long)row*512 + lane*8) = out;
  }
}

// ---------------- out projection: u = t + relu(t @ Wo + bo), bf16 out ----------------
__global__ __launch_bounds__(256) void out_mfma(
    const unsigned short* t_bf, const unsigned short* Wt, const float* bo,
    unsigned short* u_bf)
{
  const int row0 = blockIdx.y*64, col0 = blockIdx.x*128;
  __shared__ unsigned short As[2][64][40];
  __shared__ unsigned short Ws[2][128][40];
  const int t = threadIdx.x;
  const int lane = t & 63, wid = t >> 6;
  const int ln = lane & 15, quad = lane >> 4;
  const int wy = wid >> 1, wx = wid & 1;   // wave: 32 rows x 64 cols
  f32x4 acc[2][4];
  #pragma unroll
  for (int i=0;i<2;++i){
    #pragma unroll
    for (int j=0;j<4;++j) acc[i][j] = (f32x4){0.f,0.f,0.f,0.f};
  }
  const int ar = t>>2, ac0 = (t&3)*8;
  const int wr = t>>1, wc0 = (t&1)*16;
  const unsigned short* Arow = t_bf + (long)(row0+ar)*512 + ac0;
  const unsigned short* Wrow = Wt   + (long)(col0+wr)*512 + wc0;
  uint4 a0 = *(const uint4*)(Arow);
  uint4 w0 = *(const uint4*)(Wrow);
  uint4 w1 = *(const uint4*)(Wrow + 8);
  *(uint4*)&As[0][ar][ac0] = a0;
  *(uint4*)&Ws[0][wr][wc0]   = w0;
  *(uint4*)&Ws[0][wr][wc0+8] = w1;
  __syncthreads();
  for (int it=0; it<16; ++it){
    const int cur = it & 1;
    if (it < 15){
      a0 = *(const uint4*)(Arow + (it+1)*32);
      w0 = *(const uint4*)(Wrow + (it+1)*32);
      w1 = *(const uint4*)(Wrow + (it+1)*32 + 8);
    }
    short8 a[2], b[4];
    #pragma unroll
    for (int mt=0;mt<2;++mt) a[mt] = *(const short8*)&As[cur][wy*32+mt*16+ln][quad*8];
    #pragma unroll
    for (int nt=0;nt<4;++nt) b[nt] = *(const short8*)&Ws[cur][wx*64+nt*16+ln][quad*8];
    #pragma unroll
    for (int mt=0;mt<2;++mt){
      #pragma unroll
      for (int nt=0;nt<4;++nt)
        acc[mt][nt] = __builtin_amdgcn_mfma_f32_16x16x32_bf16(a[mt], b[nt], acc[mt][nt], 0,0,0);
    }
    if (it < 15){
      *(uint4*)&As[cur^1][ar][ac0] = a0;
      *(uint4*)&Ws[cur^1][wr][wc0]   = w0;
      *(uint4*)&Ws[cur^1][wr][wc0+8] = w1;
    }
    __syncthreads();
  }
  float bias_v[4];
  #pragma unroll
  for (int nt=0;nt<4;++nt) bias_v[nt] = bo[col0 + wx*64 + nt*16 + ln];
  #pragma unroll
  for (int mt=0;mt<2;++mt){
    int row = row0 + wy*32 + mt*16 + quad*4;
    #pragma unroll
    for (int nt=0;nt<4;++nt){
      int col = col0 + wx*64 + nt*16 + ln;
      #pragma unroll
      for (int r=0;r<4;++r){
        long idx = (long)(row+r)*512 + col;
        float u = acc[mt][nt][r] + bias_v[nt];
        u = fmaxf(u, 0.f);
        u_bf[idx] = f2b(bfu(t_bf[idx]) + u);
      }
    }
  }
}

extern "C" void kernel_launch(void* const* d_in, const int* in_sizes, int n_in,
                              void* d_out, int out_size, void* d_ws, size_t ws_size,
                              hipStream_t stream)
{
  unsigned short* q_bf  = (unsigned short*)d_ws;
  unsigned short* k_bf  = q_bf  + 8192l*512;
  unsigned short* vt_bf = k_bf  + 8192l*512;
  unsigned short* t_bf  = vt_bf + 8192l*512;
  unsigned short* wt    = t_bf  + 8192l*512;
  unsigned short* qin   = wt + 4l*512*512;
  unsigned short* kin   = qin + 4194304;
  unsigned short* o_bf  = qin;   // alias: valid after proj_mfma
  unsigned short* u_bf  = kin;   // alias: valid after proj_mfma

  hipLaunchKernelGGL(prep_inputs, dim3(4352), dim3(256), 0, stream,
                     (const float*)d_in[5], (const float*)d_in[7],
                     (const float*)d_in[9], (const float*)d_in[11],
                     (const float*)d_in[0], (const float*)d_in[1], wt, qin);
  hipLaunchKernelGGL(proj_mfma, dim3(4,64,3), dim3(256), 0, stream,
                     qin, kin, wt,
                     (const float*)d_in[6], (const float*)d_in[8],
                     (const float*)d_in[10], q_bf, k_bf, vt_bf);
  hipLaunchKernelGGL(attn_mfma, dim3(64,8), dim3(512), 0, stream,
                     q_bf, k_bf, vt_bf,
                     (const float*)d_in[2], (const float*)d_in[3], o_bf);
  hipLaunchKernelGGL(ln_kernel, dim3(2048), dim3(256), 0, stream,
                     o_bf, (void*)t_bf, 0, (const float*)d_in[13], (const float*)d_in[14]);
  hipLaunchKernelGGL(out_mfma, dim3(4,128), dim3(256), 0, stream,
                     t_bf, wt + 3l*512*512, (const float*)d_in[12], u_bf);
  hipLaunchKernelGGL(ln_kernel, dim3(2048), dim3(256), 0, stream,
                     u_bf, d_out, 1, (const float*)d_in[15], (const float*)d_in[16]);
}

// Round 7
// 211.132 us; speedup vs baseline: 1.1466x; 1.0264x over previous
//
#include <hip/hip_runtime.h>

typedef __attribute__((ext_vector_type(8))) short short8;
typedef __attribute__((ext_vector_type(4))) float f32x4;

#define SCALE2 0.06375871571f   // (1/sqrt(512)) * log2(e)

__device__ __forceinline__ float bfu(unsigned short u){
  return __uint_as_float(((unsigned int)u) << 16);
}
__device__ __forceinline__ unsigned short f2b(float x){   // RNE
  unsigned int b = __float_as_uint(x);
  return (unsigned short)((b + 0x7fffu + ((b>>16)&1u)) >> 16);
}
// 8 contiguous f32 -> 8 bf16 packed in a uint4
__device__ __forceinline__ uint4 pack8(const float* f){
  float4 a = *(const float4*)f, b = *(const float4*)(f+4);
  uint4 r;
  r.x = (unsigned)f2b(a.x) | ((unsigned)f2b(a.y)<<16);
  r.y = (unsigned)f2b(a.z) | ((unsigned)f2b(a.w)<<16);
  r.z = (unsigned)f2b(b.x) | ((unsigned)f2b(b.y)<<16);
  r.w = (unsigned)f2b(b.z) | ((unsigned)f2b(b.w)<<16);
  return r;
}

// ---------------- weight transpose (bf16), weights only ----------------
__global__ __launch_bounds__(256) void prep_w(
    const float* Wq, const float* Wk, const float* Wv, const float* Wo,
    unsigned short* wt)
{
  const int id = blockIdx.x, t = threadIdx.x;
  const int m = id >> 6;
  const float* W = (m==0)?Wq:(m==1)?Wk:(m==2)?Wv:Wo;
  unsigned short* dst = wt + (long)m*262144;
  __shared__ unsigned short tile[64][72];
  const int n0 = ((id>>3)&7)*64, k0 = (id&7)*64;
  {
    int r = t>>2, c0 = (t&3)*16;
    uint4 u0 = pack8(W + (long)(k0+r)*512 + n0 + c0);
    uint4 u1 = pack8(W + (long)(k0+r)*512 + n0 + c0 + 8);
    unsigned short* us0 = (unsigned short*)&u0;
    unsigned short* us1 = (unsigned short*)&u1;
    #pragma unroll
    for (int i=0;i<8;++i) tile[c0+i][r] = us0[i];
    #pragma unroll
    for (int i=0;i<8;++i) tile[c0+8+i][r] = us1[i];
  }
  __syncthreads();
  {
    int n = t>>2, ks = (t&3)*16;
    *(uint4*)(dst + (long)(n0+n)*512 + k0 + ks)     = *(uint4*)&tile[n][ks];
    *(uint4*)(dst + (long)(n0+n)*512 + k0 + ks + 8) = *(uint4*)&tile[n][ks+8];
  }
}

// ---------------- QKV projection (bf16 MFMA, dbuf LDS, f32 A converted in staging) ----------------
__global__ __launch_bounds__(256) void proj_mfma(
    const float* qf, const float* kf, const unsigned short* wt,
    const float* bq, const float* bk, const float* bv,
    unsigned short* q_bf, unsigned short* k_bf, unsigned short* vt_bf)
{
  const int mat = blockIdx.z;
  const float* A = (mat==0)? qf : kf;
  const unsigned short* Wt = wt + (long)mat*262144;
  const float* bias = (mat==0)?bq:(mat==1)?bk:bv;
  const int row0 = blockIdx.y*128, col0 = blockIdx.x*128;
  __shared__ unsigned short As[2][128][40];
  __shared__ unsigned short Ws[2][128][40];
  const int t = threadIdx.x;
  const int lane = t & 63, wid = t >> 6;
  const int ln = lane & 15, quad = lane >> 4;
  const int wy = wid >> 1, wx = wid & 1;
  f32x4 acc[4][4];
  #pragma unroll
  for (int i=0;i<4;++i){
    #pragma unroll
    for (int j=0;j<4;++j) acc[i][j] = (f32x4){0.f,0.f,0.f,0.f};
  }
  const int sr = t>>1, sk0 = (t&1)*16;
  const float* Arow = A + (long)(row0+sr)*512 + sk0;
  const unsigned short* Wrow = Wt + (long)(col0+sr)*512 + sk0;
  uint4 a0 = pack8(Arow);
  uint4 a1 = pack8(Arow + 8);
  uint4 w0 = *(const uint4*)(Wrow);
  uint4 w1 = *(const uint4*)(Wrow + 8);
  *(uint4*)&As[0][sr][sk0]   = a0;
  *(uint4*)&As[0][sr][sk0+8] = a1;
  *(uint4*)&Ws[0][sr][sk0]   = w0;
  *(uint4*)&Ws[0][sr][sk0+8] = w1;
  __syncthreads();
  for (int it=0; it<16; ++it){
    const int cur = it & 1;
    if (it < 15){
      a0 = pack8(Arow + (it+1)*32);
      a1 = pack8(Arow + (it+1)*32 + 8);
      w0 = *(const uint4*)(Wrow + (it+1)*32);
      w1 = *(const uint4*)(Wrow + (it+1)*32 + 8);
    }
    short8 a[4], b[4];
    #pragma unroll
    for (int mt=0;mt<4;++mt) a[mt] = *(const short8*)&As[cur][wy*64+mt*16+ln][quad*8];
    #pragma unroll
    for (int nt=0;nt<4;++nt) b[nt] = *(const short8*)&Ws[cur][wx*64+nt*16+ln][quad*8];
    #pragma unroll
    for (int mt=0;mt<4;++mt){
      #pragma unroll
      for (int nt=0;nt<4;++nt)
        acc[mt][nt] = __builtin_amdgcn_mfma_f32_16x16x32_bf16(a[mt], b[nt], acc[mt][nt], 0,0,0);
    }
    if (it < 15){
      *(uint4*)&As[cur^1][sr][sk0]   = a0;
      *(uint4*)&As[cur^1][sr][sk0+8] = a1;
      *(uint4*)&Ws[cur^1][sr][sk0]   = w0;
      *(uint4*)&Ws[cur^1][sr][sk0+8] = w1;
    }
    __syncthreads();
  }
  float bias_v[4];
  #pragma unroll
  for (int nt=0;nt<4;++nt) bias_v[nt] = bias[col0 + wx*64 + nt*16 + ln];
  if (mat < 2){
    unsigned short* dst = (mat==0)? q_bf : k_bf;
    #pragma unroll
    for (int mt=0;mt<4;++mt){
      int row = row0 + wy*64 + mt*16 + quad*4;
      #pragma unroll
      for (int nt=0;nt<4;++nt){
        int col = col0 + wx*64 + nt*16 + ln;
        #pragma unroll
        for (int r=0;r<4;++r)
          dst[(long)(row+r)*512 + col] = f2b(acc[mt][nt][r] + bias_v[nt]);
      }
    }
  } else {
    #pragma unroll
    for (int mt=0;mt<4;++mt){
      int row = row0 + wy*64 + mt*16 + quad*4;   // token base, 4-aligned
      int bb = row >> 10, sk = row & 1023;
      #pragma unroll
      for (int nt=0;nt<4;++nt){
        int col = col0 + wx*64 + nt*16 + ln;
        int h = col >> 6, dd = col & 63;
        uint2 pk2; unsigned short* pp = (unsigned short*)&pk2;
        #pragma unroll
        for (int r=0;r<4;++r) pp[r] = f2b(acc[mt][nt][r] + bias_v[nt]);
        *(uint2*)(vt_bf + (((long)((bb*8+h)*64+dd)) << 10) + sk) = pk2;
      }
    }
  }
}

// ---------------- flash attention: R0-verified 4-wave, 32 q-rows/wave (2 strips) ----------------
__global__ __launch_bounds__(256) void attn_mfma(
    const unsigned short* q_bf, const unsigned short* k_bf, const unsigned short* vt_bf,
    const float* pres_q, const float* pres_k, unsigned short* o_bf)
{
  const int bx = blockIdx.x;
  const int b = bx >> 3, h = bx & 7;
  const int q0 = blockIdx.y * 128;
  const int t = threadIdx.x;
  const int lane = t & 63, wid = t >> 6, ln = lane & 15, quad = lane >> 4;
  __shared__ unsigned short QP[128][72];   // Q staging, then Ps (wave-private rows)
  __shared__ unsigned short Ks[2][64][72];
  __shared__ unsigned short Vt[2][64][72];
  __shared__ float pq_s[128];
  __shared__ float pk_s[2][64];
  {
    int tok = t>>1, ds = (t&1)*32;       // 128 rows, 32 shorts each half
    const unsigned short* src = q_bf + (long)(b*1024 + q0 + tok)*512 + h*64 + ds;
    *(uint4*)&QP[tok][ds]    = *(const uint4*)src;
    *(uint4*)&QP[tok][ds+8]  = *(const uint4*)(src+8);
    *(uint4*)&QP[tok][ds+16] = *(const uint4*)(src+16);
    *(uint4*)&QP[tok][ds+24] = *(const uint4*)(src+24);
  }
  {
    int tok = t>>2, ds = (t&3)*16;
    const unsigned short* sk = k_bf + (long)(b*1024 + tok)*512 + h*64 + ds;
    *(uint4*)&Ks[0][tok][ds]   = *(const uint4*)sk;
    *(uint4*)&Ks[0][tok][ds+8] = *(const uint4*)(sk+8);
    const unsigned short* sv = vt_bf + (((long)((b*8+h)*64 + tok)) << 10) + ds;
    *(uint4*)&Vt[0][tok][ds]   = *(const uint4*)sv;
    *(uint4*)&Vt[0][tok][ds+8] = *(const uint4*)(sv+8);
  }
  if (t < 128) pq_s[t] = pres_q[b*1024 + q0 + t];
  if (t < 64)  pk_s[0][t] = pres_k[b*1024 + t];
  __syncthreads();
  // Q frags for both strips (rows wid*32 + s*16 + ln)
  short8 aq[2][2];
  float av[2][4], mval[2][4];
  #pragma unroll
  for (int s=0;s<2;++s){
    aq[s][0] = *(const short8*)&QP[wid*32+s*16+ln][quad*8];
    aq[s][1] = *(const short8*)&QP[wid*32+s*16+ln][32+quad*8];
    #pragma unroll
    for (int r=0;r<4;++r){
      av[s][r] = pq_s[wid*32 + s*16 + quad*4 + r]*SCALE2;
      mval[s][r] = (av[s][r] == 0.f) ? 0.f : -43.f;
    }
  }
  f32x4 oacc[2][4];
  float lsum[2][4];
  #pragma unroll
  for (int s=0;s<2;++s){
    #pragma unroll
    for (int i=0;i<4;++i){ oacc[s][i] = (f32x4){0.f,0.f,0.f,0.f}; lsum[s][i] = 0.f; }
  }

  for (int it=0; it<16; ++it){
    const int cur = it & 1;
    const int k0n = (it+1)*64;
    uint4 pf_k0, pf_k1, pf_v0, pf_v1; float pf_p = 0.f;
    if (it < 15){
      int tok = t>>2, ds = (t&3)*16;
      const unsigned short* sk = k_bf + (long)(b*1024 + k0n + tok)*512 + h*64 + ds;
      pf_k0 = *(const uint4*)sk;
      pf_k1 = *(const uint4*)(sk+8);
      const unsigned short* sv = vt_bf + (((long)((b*8+h)*64 + tok)) << 10) + k0n + ds;
      pf_v0 = *(const uint4*)sv;
      pf_v1 = *(const uint4*)(sv+8);
      if (t < 64) pf_p = pres_k[b*1024 + k0n + t];
    }
    // S = Q K^T : each kb fragment pair feeds BOTH strips
    f32x4 s[2][4];
    #pragma unroll
    for (int st=0;st<2;++st){
      #pragma unroll
      for (int kt=0;kt<4;++kt) s[st][kt] = (f32x4){0.f,0.f,0.f,0.f};
    }
    #pragma unroll
    for (int kt=0;kt<4;++kt){
      short8 kb0 = *(const short8*)&Ks[cur][kt*16+ln][quad*8];
      short8 kb1 = *(const short8*)&Ks[cur][kt*16+ln][32+quad*8];
      #pragma unroll
      for (int st=0;st<2;++st){
        s[st][kt] = __builtin_amdgcn_mfma_f32_16x16x32_bf16(aq[st][0], kb0, s[st][kt], 0,0,0);
        s[st][kt] = __builtin_amdgcn_mfma_f32_16x16x32_bf16(aq[st][1], kb1, s[st][kt], 0,0,0);
      }
    }
    float pk4[4];
    #pragma unroll
    for (int kt=0;kt<4;++kt) pk4[kt] = pk_s[cur][kt*16+ln];
    #pragma unroll
    for (int st=0;st<2;++st){
      #pragma unroll
      for (int r=0;r<4;++r){
        #pragma unroll
        for (int kt=0;kt<4;++kt){
          float x0 = s[st][kt][r]*av[st][r];
          float x = __builtin_fmaf(pk4[kt], x0 - mval[st][r], mval[st][r]);
          float e = __builtin_amdgcn_exp2f(x);
          lsum[st][r] += e;
          QP[wid*32+st*16+quad*4+r][kt*16+ln] = (unsigned short)(__float_as_uint(e) >> 16);
        }
      }
    }
    // O += P V : each vb fragment pair feeds BOTH strips
    short8 ap[2][2];
    #pragma unroll
    for (int st=0;st<2;++st){
      ap[st][0] = *(const short8*)&QP[wid*32+st*16+ln][quad*8];
      ap[st][1] = *(const short8*)&QP[wid*32+st*16+ln][32+quad*8];
    }
    #pragma unroll
    for (int dt=0;dt<4;++dt){
      short8 vb0 = *(const short8*)&Vt[cur][dt*16+ln][quad*8];
      short8 vb1 = *(const short8*)&Vt[cur][dt*16+ln][32+quad*8];
      #pragma unroll
      for (int st=0;st<2;++st){
        oacc[st][dt] = __builtin_amdgcn_mfma_f32_16x16x32_bf16(ap[st][0], vb0, oacc[st][dt], 0,0,0);
        oacc[st][dt] = __builtin_amdgcn_mfma_f32_16x16x32_bf16(ap[st][1], vb1, oacc[st][dt], 0,0,0);
      }
    }
    if (it < 15){
      int tok = t>>2, ds = (t&3)*16;
      *(uint4*)&Ks[cur^1][tok][ds]   = pf_k0;
      *(uint4*)&Ks[cur^1][tok][ds+8] = pf_k1;
      *(uint4*)&Vt[cur^1][tok][ds]   = pf_v0;
      *(uint4*)&Vt[cur^1][tok][ds+8] = pf_v1;
      if (t < 64) pk_s[cur^1][t] = pf_p;
    }
    __syncthreads();
  }
  // epilogue: o = qh + (P V)/l  (bf16 out)
  #pragma unroll
  for (int st=0;st<2;++st){
    #pragma unroll
    for (int r=0;r<4;++r){
      float l = lsum[st][r];
      #pragma unroll
      for (int msk=1; msk<16; msk<<=1) l += __shfl_xor(l, msk);
      float inv = 1.f / l;
      int ql = wid*32 + st*16 + quad*4 + r;
      long base = (long)(b*1024 + q0 + ql)*512 + h*64;
      #pragma unroll
      for (int dt=0;dt<4;++dt){
        float qh = bfu(q_bf[base + dt*16 + ln]);
        o_bf[base + dt*16 + ln] = f2b(qh + oacc[st][dt][r]*inv);
      }
    }
  }
}

// ---------------- fused: t = LN0(o); u = t + relu(t@Wo+bo); out = LN1(u) (f32) ----------------
// 256 blocks x 512 thr; block owns 32 full rows. o staged+LN0'd in LDS (To), GEMM over
// k-tiled Wo panels (dbuf, verified fragment patterns), u written to reused LDS, LN1
// epilogue writes f32 output. Eliminates t_bf/u_bf global round-trips and 2 launches.
__global__ __launch_bounds__(512, 2) void out_ln(
    const unsigned short* o_bf, const unsigned short* Wt, const float* bo,
    const float* g0, const float* b0, const float* g1, const float* b1,
    float* out)
{
  const int row0 = blockIdx.x * 32;
  const int t = threadIdx.x;
  const int lane = t & 63, wid = t >> 6, ln = lane & 15, quad = lane >> 4;

  __shared__ unsigned short To[32][520];
  __shared__ unsigned short Ws[2][512][40];

  // stage o rows (32 x 512 bf16)
  {
    int r = t >> 4, c0 = (t & 15) * 32;
    const unsigned short* src = o_bf + (long)(row0 + r)*512 + c0;
    #pragma unroll
    for (int i=0;i<4;++i)
      *(uint4*)&To[r][c0 + i*8] = *(const uint4*)(src + i*8);
  }
  // stage W k-tile 0 (512 n-rows x 32 k)
  {
    const unsigned short* wr = Wt + (long)t*512;
    #pragma unroll
    for (int i=0;i<4;++i)
      *(uint4*)&Ws[0][t][i*8] = *(const uint4*)(wr + i*8);
  }
  __syncthreads();
  // LN0 in LDS: wave handles rows wid*4 .. +3 (verified ln math)
  {
    float gv[8], bv[8];
    *(float4*)&gv[0] = *(const float4*)(g0 + lane*8);
    *(float4*)&gv[4] = *(const float4*)(g0 + lane*8 + 4);
    *(float4*)&bv[0] = *(const float4*)(b0 + lane*8);
    *(float4*)&bv[4] = *(const float4*)(b0 + lane*8 + 4);
    #pragma unroll
    for (int i=0;i<4;++i){
      int r = wid*4 + i;
      uint4 raw = *(const uint4*)&To[r][lane*8];
      const unsigned short* rs16 = (const unsigned short*)&raw;
      float v[8];
      #pragma unroll
      for (int c=0;c<8;++c) v[c] = bfu(rs16[c]);
      float sum = 0.f;
      #pragma unroll
      for (int c=0;c<8;++c) sum += v[c];
      #pragma unroll
      for (int msk=1; msk<64; msk<<=1) sum += __shfl_xor(sum, msk);
      float mu = sum * (1.f/512.f);
      float var = 0.f;
      #pragma unroll
      for (int c=0;c<8;++c){ v[c] -= mu; var += v[c]*v[c]; }
      #pragma unroll
      for (int msk=1; msk<64; msk<<=1) var += __shfl_xor(var, msk);
      float rs = rsqrtf(var*(1.f/512.f) + 1e-5f);
      uint4 o4; unsigned short* os = (unsigned short*)&o4;
      #pragma unroll
      for (int c=0;c<8;++c) os[c] = f2b(v[c]*rs*gv[c] + bv[c]);
      *(uint4*)&To[r][lane*8] = o4;
    }
  }
  __syncthreads();

  // GEMM: T(32x512) @ Wo(512x512) with k-tiled dbuf panels; wave wid owns cols wid*64
  f32x4 acc[2][4];
  #pragma unroll
  for (int i=0;i<2;++i){
    #pragma unroll
    for (int j=0;j<4;++j) acc[i][j] = (f32x4){0.f,0.f,0.f,0.f};
  }
  for (int it=0; it<16; ++it){
    const int cur = it & 1;
    uint4 pw0, pw1, pw2, pw3;
    if (it < 15){
      const unsigned short* wr = Wt + (long)t*512 + (it+1)*32;
      pw0 = *(const uint4*)(wr);
      pw1 = *(const uint4*)(wr + 8);
      pw2 = *(const uint4*)(wr + 16);
      pw3 = *(const uint4*)(wr + 24);
    }
    short8 a[2], b[4];
    a[0] = *(const short8*)&To[ln][it*32 + quad*8];
    a[1] = *(const short8*)&To[16+ln][it*32 + quad*8];
    #pragma unroll
    for (int nt=0;nt<4;++nt) b[nt] = *(const short8*)&Ws[cur][wid*64 + nt*16 + ln][quad*8];
    #pragma unroll
    for (int mt=0;mt<2;++mt){
      #pragma unroll
      for (int nt=0;nt<4;++nt)
        acc[mt][nt] = __builtin_amdgcn_mfma_f32_16x16x32_bf16(a[mt], b[nt], acc[mt][nt], 0,0,0);
    }
    if (it < 15){
      *(uint4*)&Ws[cur^1][t][0]  = pw0;
      *(uint4*)&Ws[cur^1][t][8]  = pw1;
      *(uint4*)&Ws[cur^1][t][16] = pw2;
      *(uint4*)&Ws[cur^1][t][24] = pw3;
    }
    __syncthreads();
  }

  // u = t + relu(acc + bo) -> Us (reuses Ws storage; all GEMM reads done)
  unsigned short* Us = &Ws[0][0][0];   // [32][520]
  {
    float bo_v[4];
    #pragma unroll
    for (int nt=0;nt<4;++nt) bo_v[nt] = bo[wid*64 + nt*16 + ln];
    #pragma unroll
    for (int mt=0;mt<2;++mt){
      int row = mt*16 + quad*4;
      #pragma unroll
      for (int nt=0;nt<4;++nt){
        int col = wid*64 + nt*16 + ln;
        #pragma unroll
        for (int r=0;r<4;++r){
          float tv = bfu(To[row+r][col]);
          float u = tv + fmaxf(acc[mt][nt][r] + bo_v[nt], 0.f);
          Us[(long)(row+r)*520 + col] = f2b(u);
        }
      }
    }
  }
  __syncthreads();
  // LN1 + f32 global write: wave handles rows wid*4 .. +3
  {
    float gv[8], bv[8];
    *(float4*)&gv[0] = *(const float4*)(g1 + lane*8);
    *(float4*)&gv[4] = *(const float4*)(g1 + lane*8 + 4);
    *(float4*)&bv[0] = *(const float4*)(b1 + lane*8);
    *(float4*)&bv[4] = *(const float4*)(b1 + lane*8 + 4);
    #pragma unroll
    for (int i=0;i<4;++i){
      int r = wid*4 + i;
      uint4 raw = *(const uint4*)&Us[(long)r*520 + lane*8];
      const unsigned short* rs16 = (const unsigned short*)&raw;
      float v[8];
      #pragma unroll
      for (int c=0;c<8;++c) v[c] = bfu(rs16[c]);
      float sum = 0.f;
      #pragma unroll
      for (int c=0;c<8;++c) sum += v[c];
      #pragma unroll
      for (int msk=1; msk<64; msk<<=1) sum += __shfl_xor(sum, msk);
      float mu = sum * (1.f/512.f);
      float var = 0.f;
      #pragma unroll
      for (int c=0;c<8;++c){ v[c] -= mu; var += v[c]*v[c]; }
      #pragma unroll
      for (int msk=1; msk<64; msk<<=1) var += __shfl_xor(var, msk);
      float rs = rsqrtf(var*(1.f/512.f) + 1e-5f);
      float y[8];
      #pragma unroll
      for (int c=0;c<8;++c) y[c] = v[c]*rs*gv[c] + bv[c];
      float* dst = out + (long)(row0 + r)*512 + lane*8;
      *(float4*)dst       = *(float4*)&y[0];
      *(float4*)(dst + 4) = *(float4*)&y[4];
    }
  }
}

extern "C" void kernel_launch(void* const* d_in, const int* in_sizes, int n_in,
                              void* d_out, int out_size, void* d_ws, size_t ws_size,
                              hipStream_t stream)
{
  unsigned short* q_bf  = (unsigned short*)d_ws;
  unsigned short* k_bf  = q_bf  + 8192l*512;
  unsigned short* vt_bf = k_bf  + 8192l*512;
  unsigned short* o_bf  = vt_bf + 8192l*512;
  unsigned short* wt    = o_bf  + 8192l*512;

  hipLaunchKernelGGL(prep_w, dim3(256), dim3(256), 0, stream,
                     (const float*)d_in[5], (const float*)d_in[7],
                     (const float*)d_in[9], (const float*)d_in[11], wt);
  hipLaunchKernelGGL(proj_mfma, dim3(4,64,3), dim3(256), 0, stream,
                     (const float*)d_in[0], (const float*)d_in[1], wt,
                     (const float*)d_in[6], (const float*)d_in[8],
                     (const float*)d_in[10], q_bf, k_bf, vt_bf);
  hipLaunchKernelGGL(attn_mfma, dim3(64,8), dim3(256), 0, stream,
                     q_bf, k_bf, vt_bf,
                     (const float*)d_in[2], (const float*)d_in[3], o_bf);
  hipLaunchKernelGGL(out_ln, dim3(256), dim3(512), 0, stream,
                     o_bf, wt + 3l*512*512, (const float*)d_in[12],
                     (const float*)d_in[13], (const float*)d_in[14],
                     (const float*)d_in[15], (const float*)d_in[16],
                     (float*)d_out);
}

// Round 8
// 209.486 us; speedup vs baseline: 1.1556x; 1.0079x over previous
//
#include <hip/hip_runtime.h>

typedef __attribute__((ext_vector_type(8))) short short8;
typedef __attribute__((ext_vector_type(4))) float f32x4;

#define SCALE2 0.06375871571f   // (1/sqrt(512)) * log2(e)

__device__ __forceinline__ float bfu(unsigned short u){
  return __uint_as_float(((unsigned int)u) << 16);
}
__device__ __forceinline__ unsigned short f2b(float x){   // RNE
  unsigned int b = __float_as_uint(x);
  return (unsigned short)((b + 0x7fffu + ((b>>16)&1u)) >> 16);
}
// 8 contiguous f32 -> 8 bf16 packed in a uint4
__device__ __forceinline__ uint4 pack8(const float* f){
  float4 a = *(const float4*)f, b = *(const float4*)(f+4);
  uint4 r;
  r.x = (unsigned)f2b(a.x) | ((unsigned)f2b(a.y)<<16);
  r.y = (unsigned)f2b(a.z) | ((unsigned)f2b(a.w)<<16);
  r.z = (unsigned)f2b(b.x) | ((unsigned)f2b(b.y)<<16);
  r.w = (unsigned)f2b(b.z) | ((unsigned)f2b(b.w)<<16);
  return r;
}

// ---------------- fused input prep: weight transpose + q/k convert ----------------
__global__ __launch_bounds__(256) void prep_inputs(
    const float* Wq, const float* Wk, const float* Wv, const float* Wo,
    const float* q, const float* k, unsigned short* wt, unsigned short* qk_dst)
{
  const int id = blockIdx.x, t = threadIdx.x;
  if (id < 256){
    const int m = id >> 6;
    const float* W = (m==0)?Wq:(m==1)?Wk:(m==2)?Wv:Wo;
    unsigned short* dst = wt + (long)m*262144;
    __shared__ unsigned short tile[64][72];
    const int n0 = ((id>>3)&7)*64, k0 = (id&7)*64;
    {
      int r = t>>2, c0 = (t&3)*16;
      uint4 u0 = pack8(W + (long)(k0+r)*512 + n0 + c0);
      uint4 u1 = pack8(W + (long)(k0+r)*512 + n0 + c0 + 8);
      unsigned short* us0 = (unsigned short*)&u0;
      unsigned short* us1 = (unsigned short*)&u1;
      #pragma unroll
      for (int i=0;i<8;++i) tile[c0+i][r] = us0[i];
      #pragma unroll
      for (int i=0;i<8;++i) tile[c0+8+i][r] = us1[i];
    }
    __syncthreads();
    {
      int n = t>>2, ks = (t&3)*16;
      *(uint4*)(dst + (long)(n0+n)*512 + k0 + ks)     = *(uint4*)&tile[n][ks];
      *(uint4*)(dst + (long)(n0+n)*512 + k0 + ks + 8) = *(uint4*)&tile[n][ks+8];
    }
  } else {
    long i = ((long)(id-256)*256 + t)*8;
    const float* src = (i < 4194304) ? q + i : k + (i - 4194304);
    *(uint4*)(qk_dst + i) = pack8(src);
  }
}

// ---------------- QKV projection (bf16 MFMA, dbuf LDS, 1 barrier/iter) ----------------
__global__ __launch_bounds__(256) void proj_mfma(
    const unsigned short* qin, const unsigned short* kin, const unsigned short* wt,
    const float* bq, const float* bk, const float* bv,
    unsigned short* q_bf, unsigned short* k_bf, unsigned short* vt_bf)
{
  const int mat = blockIdx.z;
  const unsigned short* A = (mat==0)? qin : kin;
  const unsigned short* Wt = wt + (long)mat*262144;
  const float* bias = (mat==0)?bq:(mat==1)?bk:bv;
  const int row0 = blockIdx.y*128, col0 = blockIdx.x*128;
  __shared__ unsigned short As[2][128][40];
  __shared__ unsigned short Ws[2][128][40];
  const int t = threadIdx.x;
  const int lane = t & 63, wid = t >> 6;
  const int ln = lane & 15, quad = lane >> 4;
  const int wy = wid >> 1, wx = wid & 1;
  f32x4 acc[4][4];
  #pragma unroll
  for (int i=0;i<4;++i){
    #pragma unroll
    for (int j=0;j<4;++j) acc[i][j] = (f32x4){0.f,0.f,0.f,0.f};
  }
  const int sr = t>>1, sk0 = (t&1)*16;
  const unsigned short* Arow = A  + (long)(row0+sr)*512 + sk0;
  const unsigned short* Wrow = Wt + (long)(col0+sr)*512 + sk0;
  uint4 a0 = *(const uint4*)(Arow);
  uint4 a1 = *(const uint4*)(Arow + 8);
  uint4 w0 = *(const uint4*)(Wrow);
  uint4 w1 = *(const uint4*)(Wrow + 8);
  *(uint4*)&As[0][sr][sk0]   = a0;
  *(uint4*)&As[0][sr][sk0+8] = a1;
  *(uint4*)&Ws[0][sr][sk0]   = w0;
  *(uint4*)&Ws[0][sr][sk0+8] = w1;
  __syncthreads();
  for (int it=0; it<16; ++it){
    const int cur = it & 1;
    if (it < 15){
      a0 = *(const uint4*)(Arow + (it+1)*32);
      a1 = *(const uint4*)(Arow + (it+1)*32 + 8);
      w0 = *(const uint4*)(Wrow + (it+1)*32);
      w1 = *(const uint4*)(Wrow + (it+1)*32 + 8);
    }
    short8 a[4], b[4];
    #pragma unroll
    for (int mt=0;mt<4;++mt) a[mt] = *(const short8*)&As[cur][wy*64+mt*16+ln][quad*8];
    #pragma unroll
    for (int nt=0;nt<4;++nt) b[nt] = *(const short8*)&Ws[cur][wx*64+nt*16+ln][quad*8];
    #pragma unroll
    for (int mt=0;mt<4;++mt){
      #pragma unroll
      for (int nt=0;nt<4;++nt)
        acc[mt][nt] = __builtin_amdgcn_mfma_f32_16x16x32_bf16(a[mt], b[nt], acc[mt][nt], 0,0,0);
    }
    if (it < 15){
      *(uint4*)&As[cur^1][sr][sk0]   = a0;
      *(uint4*)&As[cur^1][sr][sk0+8] = a1;
      *(uint4*)&Ws[cur^1][sr][sk0]   = w0;
      *(uint4*)&Ws[cur^1][sr][sk0+8] = w1;
    }
    __syncthreads();
  }
  float bias_v[4];
  #pragma unroll
  for (int nt=0;nt<4;++nt) bias_v[nt] = bias[col0 + wx*64 + nt*16 + ln];
  if (mat < 2){
    unsigned short* dst = (mat==0)? q_bf : k_bf;
    #pragma unroll
    for (int mt=0;mt<4;++mt){
      int row = row0 + wy*64 + mt*16 + quad*4;
      #pragma unroll
      for (int nt=0;nt<4;++nt){
        int col = col0 + wx*64 + nt*16 + ln;
        #pragma unroll
        for (int r=0;r<4;++r)
          dst[(long)(row+r)*512 + col] = f2b(acc[mt][nt][r] + bias_v[nt]);
      }
    }
  } else {
    #pragma unroll
    for (int mt=0;mt<4;++mt){
      int row = row0 + wy*64 + mt*16 + quad*4;   // token base, 4-aligned
      int bb = row >> 10, sk = row & 1023;
      #pragma unroll
      for (int nt=0;nt<4;++nt){
        int col = col0 + wx*64 + nt*16 + ln;
        int h = col >> 6, dd = col & 63;
        uint2 pk2; unsigned short* pp = (unsigned short*)&pk2;
        #pragma unroll
        for (int r=0;r<4;++r) pp[r] = f2b(acc[mt][nt][r] + bias_v[nt]);
        *(uint2*)(vt_bf + (((long)((bb*8+h)*64+dd)) << 10) + sk) = pk2;
      }
    }
  }
}

// ---------------- flash attention: R0-verified 4-wave, 32 q-rows/wave (2 strips) ----------------
__global__ __launch_bounds__(256) void attn_mfma(
    const unsigned short* q_bf, const unsigned short* k_bf, const unsigned short* vt_bf,
    const float* pres_q, const float* pres_k, unsigned short* o_bf)
{
  const int bx = blockIdx.x;
  const int b = bx >> 3, h = bx & 7;
  const int q0 = blockIdx.y * 128;
  const int t = threadIdx.x;
  const int lane = t & 63, wid = t >> 6, ln = lane & 15, quad = lane >> 4;
  __shared__ unsigned short QP[128][72];   // Q staging, then Ps (wave-private rows)
  __shared__ unsigned short Ks[2][64][72];
  __shared__ unsigned short Vt[2][64][72];
  __shared__ float pq_s[128];
  __shared__ float pk_s[2][64];
  {
    int tok = t>>1, ds = (t&1)*32;       // 128 rows, 32 shorts each half
    const unsigned short* src = q_bf + (long)(b*1024 + q0 + tok)*512 + h*64 + ds;
    *(uint4*)&QP[tok][ds]    = *(const uint4*)src;
    *(uint4*)&QP[tok][ds+8]  = *(const uint4*)(src+8);
    *(uint4*)&QP[tok][ds+16] = *(const uint4*)(src+16);
    *(uint4*)&QP[tok][ds+24] = *(const uint4*)(src+24);
  }
  {
    int tok = t>>2, ds = (t&3)*16;
    const unsigned short* sk = k_bf + (long)(b*1024 + tok)*512 + h*64 + ds;
    *(uint4*)&Ks[0][tok][ds]   = *(const uint4*)sk;
    *(uint4*)&Ks[0][tok][ds+8] = *(const uint4*)(sk+8);
    const unsigned short* sv = vt_bf + (((long)((b*8+h)*64 + tok)) << 10) + ds;
    *(uint4*)&Vt[0][tok][ds]   = *(const uint4*)sv;
    *(uint4*)&Vt[0][tok][ds+8] = *(const uint4*)(sv+8);
  }
  if (t < 128) pq_s[t] = pres_q[b*1024 + q0 + t];
  if (t < 64)  pk_s[0][t] = pres_k[b*1024 + t];
  __syncthreads();
  // Q frags for both strips (rows wid*32 + s*16 + ln)
  short8 aq[2][2];
  float av[2][4], mval[2][4];
  #pragma unroll
  for (int s=0;s<2;++s){
    aq[s][0] = *(const short8*)&QP[wid*32+s*16+ln][quad*8];
    aq[s][1] = *(const short8*)&QP[wid*32+s*16+ln][32+quad*8];
    #pragma unroll
    for (int r=0;r<4;++r){
      av[s][r] = pq_s[wid*32 + s*16 + quad*4 + r]*SCALE2;
      mval[s][r] = (av[s][r] == 0.f) ? 0.f : -43.f;
    }
  }
  f32x4 oacc[2][4];
  float lsum[2][4];
  #pragma unroll
  for (int s=0;s<2;++s){
    #pragma unroll
    for (int i=0;i<4;++i){ oacc[s][i] = (f32x4){0.f,0.f,0.f,0.f}; lsum[s][i] = 0.f; }
  }

  for (int it=0; it<16; ++it){
    const int cur = it & 1;
    const int k0n = (it+1)*64;
    uint4 pf_k0, pf_k1, pf_v0, pf_v1; float pf_p = 0.f;
    if (it < 15){
      int tok = t>>2, ds = (t&3)*16;
      const unsigned short* sk = k_bf + (long)(b*1024 + k0n + tok)*512 + h*64 + ds;
      pf_k0 = *(const uint4*)sk;
      pf_k1 = *(const uint4*)(sk+8);
      const unsigned short* sv = vt_bf + (((long)((b*8+h)*64 + tok)) << 10) + k0n + ds;
      pf_v0 = *(const uint4*)sv;
      pf_v1 = *(const uint4*)(sv+8);
      if (t < 64) pf_p = pres_k[b*1024 + k0n + t];
    }
    // S = Q K^T : each kb fragment pair feeds BOTH strips
    f32x4 s[2][4];
    #pragma unroll
    for (int st=0;st<2;++st){
      #pragma unroll
      for (int kt=0;kt<4;++kt) s[st][kt] = (f32x4){0.f,0.f,0.f,0.f};
    }
    #pragma unroll
    for (int kt=0;kt<4;++kt){
      short8 kb0 = *(const short8*)&Ks[cur][kt*16+ln][quad*8];
      short8 kb1 = *(const short8*)&Ks[cur][kt*16+ln][32+quad*8];
      #pragma unroll
      for (int st=0;st<2;++st){
        s[st][kt] = __builtin_amdgcn_mfma_f32_16x16x32_bf16(aq[st][0], kb0, s[st][kt], 0,0,0);
        s[st][kt] = __builtin_amdgcn_mfma_f32_16x16x32_bf16(aq[st][1], kb1, s[st][kt], 0,0,0);
      }
    }
    float pk4[4];
    #pragma unroll
    for (int kt=0;kt<4;++kt) pk4[kt] = pk_s[cur][kt*16+ln];
    #pragma unroll
    for (int st=0;st<2;++st){
      #pragma unroll
      for (int r=0;r<4;++r){
        #pragma unroll
        for (int kt=0;kt<4;++kt){
          float x0 = s[st][kt][r]*av[st][r];
          float x = __builtin_fmaf(pk4[kt], x0 - mval[st][r], mval[st][r]);
          float e = __builtin_amdgcn_exp2f(x);
          lsum[st][r] += e;
          QP[wid*32+st*16+quad*4+r][kt*16+ln] = (unsigned short)(__float_as_uint(e) >> 16);
        }
      }
    }
    // O += P V : each vb fragment pair feeds BOTH strips
    short8 ap[2][2];
    #pragma unroll
    for (int st=0;st<2;++st){
      ap[st][0] = *(const short8*)&QP[wid*32+st*16+ln][quad*8];
      ap[st][1] = *(const short8*)&QP[wid*32+st*16+ln][32+quad*8];
    }
    #pragma unroll
    for (int dt=0;dt<4;++dt){
      short8 vb0 = *(const short8*)&Vt[cur][dt*16+ln][quad*8];
      short8 vb1 = *(const short8*)&Vt[cur][dt*16+ln][32+quad*8];
      #pragma unroll
      for (int st=0;st<2;++st){
        oacc[st][dt] = __builtin_amdgcn_mfma_f32_16x16x32_bf16(ap[st][0], vb0, oacc[st][dt], 0,0,0);
        oacc[st][dt] = __builtin_amdgcn_mfma_f32_16x16x32_bf16(ap[st][1], vb1, oacc[st][dt], 0,0,0);
      }
    }
    if (it < 15){
      int tok = t>>2, ds = (t&3)*16;
      *(uint4*)&Ks[cur^1][tok][ds]   = pf_k0;
      *(uint4*)&Ks[cur^1][tok][ds+8] = pf_k1;
      *(uint4*)&Vt[cur^1][tok][ds]   = pf_v0;
      *(uint4*)&Vt[cur^1][tok][ds+8] = pf_v1;
      if (t < 64) pk_s[cur^1][t] = pf_p;
    }
    __syncthreads();
  }
  // epilogue: o = qh + (P V)/l  (bf16 out)
  #pragma unroll
  for (int st=0;st<2;++st){
    #pragma unroll
    for (int r=0;r<4;++r){
      float l = lsum[st][r];
      #pragma unroll
      for (int msk=1; msk<16; msk<<=1) l += __shfl_xor(l, msk);
      float inv = 1.f / l;
      int ql = wid*32 + st*16 + quad*4 + r;
      long base = (long)(b*1024 + q0 + ql)*512 + h*64;
      #pragma unroll
      for (int dt=0;dt<4;++dt){
        float qh = bfu(q_bf[base + dt*16 + ln]);
        o_bf[base + dt*16 + ln] = f2b(qh + oacc[st][dt][r]*inv);
      }
    }
  }
}

// ---------------- fused: t = LN0(o); u = t + relu(t@Wo+bo); out = LN1(u) (f32) ----------------
// 256 blocks x 512 thr; block owns 32 full rows. o staged+LN0'd in LDS (To), GEMM over
// k-tiled Wo panels (dbuf, verified fragment patterns), u written to reused LDS, LN1
// epilogue writes f32 output. Eliminates t_bf/u_bf global round-trips and 2 launches.
__global__ __launch_bounds__(512, 2) void out_ln(
    const unsigned short* o_bf, const unsigned short* Wt, const float* bo,
    const float* g0, const float* b0, const float* g1, const float* b1,
    float* out)
{
  const int row0 = blockIdx.x * 32;
  const int t = threadIdx.x;
  const int lane = t & 63, wid = t >> 6, ln = lane & 15, quad = lane >> 4;

  __shared__ unsigned short To[32][520];
  __shared__ unsigned short Ws[2][512][40];

  // stage o rows (32 x 512 bf16)
  {
    int r = t >> 4, c0 = (t & 15) * 32;
    const unsigned short* src = o_bf + (long)(row0 + r)*512 + c0;
    #pragma unroll
    for (int i=0;i<4;++i)
      *(uint4*)&To[r][c0 + i*8] = *(const uint4*)(src + i*8);
  }
  // stage W k-tile 0 (512 n-rows x 32 k)
  {
    const unsigned short* wr = Wt + (long)t*512;
    #pragma unroll
    for (int i=0;i<4;++i)
      *(uint4*)&Ws[0][t][i*8] = *(const uint4*)(wr + i*8);
  }
  __syncthreads();
  // LN0 in LDS: wave handles rows wid*4 .. +3 (verified ln math)
  {
    float gv[8], bv[8];
    *(float4*)&gv[0] = *(const float4*)(g0 + lane*8);
    *(float4*)&gv[4] = *(const float4*)(g0 + lane*8 + 4);
    *(float4*)&bv[0] = *(const float4*)(b0 + lane*8);
    *(float4*)&bv[4] = *(const float4*)(b0 + lane*8 + 4);
    #pragma unroll
    for (int i=0;i<4;++i){
      int r = wid*4 + i;
      uint4 raw = *(const uint4*)&To[r][lane*8];
      const unsigned short* rs16 = (const unsigned short*)&raw;
      float v[8];
      #pragma unroll
      for (int c=0;c<8;++c) v[c] = bfu(rs16[c]);
      float sum = 0.f;
      #pragma unroll
      for (int c=0;c<8;++c) sum += v[c];
      #pragma unroll
      for (int msk=1; msk<64; msk<<=1) sum += __shfl_xor(sum, msk);
      float mu = sum * (1.f/512.f);
      float var = 0.f;
      #pragma unroll
      for (int c=0;c<8;++c){ v[c] -= mu; var += v[c]*v[c]; }
      #pragma unroll
      for (int msk=1; msk<64; msk<<=1) var += __shfl_xor(var, msk);
      float rs = rsqrtf(var*(1.f/512.f) + 1e-5f);
      uint4 o4; unsigned short* os = (unsigned short*)&o4;
      #pragma unroll
      for (int c=0;c<8;++c) os[c] = f2b(v[c]*rs*gv[c] + bv[c]);
      *(uint4*)&To[r][lane*8] = o4;
    }
  }
  __syncthreads();

  // GEMM: T(32x512) @ Wo(512x512) with k-tiled dbuf panels; wave wid owns cols wid*64
  f32x4 acc[2][4];
  #pragma unroll
  for (int i=0;i<2;++i){
    #pragma unroll
    for (int j=0;j<4;++j) acc[i][j] = (f32x4){0.f,0.f,0.f,0.f};
  }
  for (int it=0; it<16; ++it){
    const int cur = it & 1;
    uint4 pw0, pw1, pw2, pw3;
    if (it < 15){
      const unsigned short* wr = Wt + (long)t*512 + (it+1)*32;
      pw0 = *(const uint4*)(wr);
      pw1 = *(const uint4*)(wr + 8);
      pw2 = *(const uint4*)(wr + 16);
      pw3 = *(const uint4*)(wr + 24);
    }
    short8 a[2], b[4];
    a[0] = *(const short8*)&To[ln][it*32 + quad*8];
    a[1] = *(const short8*)&To[16+ln][it*32 + quad*8];
    #pragma unroll
    for (int nt=0;nt<4;++nt) b[nt] = *(const short8*)&Ws[cur][wid*64 + nt*16 + ln][quad*8];
    #pragma unroll
    for (int mt=0;mt<2;++mt){
      #pragma unroll
      for (int nt=0;nt<4;++nt)
        acc[mt][nt] = __builtin_amdgcn_mfma_f32_16x16x32_bf16(a[mt], b[nt], acc[mt][nt], 0,0,0);
    }
    if (it < 15){
      *(uint4*)&Ws[cur^1][t][0]  = pw0;
      *(uint4*)&Ws[cur^1][t][8]  = pw1;
      *(uint4*)&Ws[cur^1][t][16] = pw2;
      *(uint4*)&Ws[cur^1][t][24] = pw3;
    }
    __syncthreads();
  }

  // u = t + relu(acc + bo) -> Us (reuses Ws storage; all GEMM reads done)
  unsigned short* Us = &Ws[0][0][0];   // [32][520]
  {
    float bo_v[4];
    #pragma unroll
    for (int nt=0;nt<4;++nt) bo_v[nt] = bo[wid*64 + nt*16 + ln];
    #pragma unroll
    for (int mt=0;mt<2;++mt){
      int row = mt*16 + quad*4;
      #pragma unroll
      for (int nt=0;nt<4;++nt){
        int col = wid*64 + nt*16 + ln;
        #pragma unroll
        for (int r=0;r<4;++r){
          float tv = bfu(To[row+r][col]);
          float u = tv + fmaxf(acc[mt][nt][r] + bo_v[nt], 0.f);
          Us[(long)(row+r)*520 + col] = f2b(u);
        }
      }
    }
  }
  __syncthreads();
  // LN1 + f32 global write: wave handles rows wid*4 .. +3
  {
    float gv[8], bv[8];
    *(float4*)&gv[0] = *(const float4*)(g1 + lane*8);
    *(float4*)&gv[4] = *(const float4*)(g1 + lane*8 + 4);
    *(float4*)&bv[0] = *(const float4*)(b1 + lane*8);
    *(float4*)&bv[4] = *(const float4*)(b1 + lane*8 + 4);
    #pragma unroll
    for (int i=0;i<4;++i){
      int r = wid*4 + i;
      uint4 raw = *(const uint4*)&Us[(long)r*520 + lane*8];
      const unsigned short* rs16 = (const unsigned short*)&raw;
      float v[8];
      #pragma unroll
      for (int c=0;c<8;++c) v[c] = bfu(rs16[c]);
      float sum = 0.f;
      #pragma unroll
      for (int c=0;c<8;++c) sum += v[c];
      #pragma unroll
      for (int msk=1; msk<64; msk<<=1) sum += __shfl_xor(sum, msk);
      float mu = sum * (1.f/512.f);
      float var = 0.f;
      #pragma unroll
      for (int c=0;c<8;++c){ v[c] -= mu; var += v[c]*v[c]; }
      #pragma unroll
      for (int msk=1; msk<64; msk<<=1) var += __shfl_xor(var, msk);
      float rs = rsqrtf(var*(1.f/512.f) + 1e-5f);
      float y[8];
      #pragma unroll
      for (int c=0;c<8;++c) y[c] = v[c]*rs*gv[c] + bv[c];
      float* dst = out + (long)(row0 + r)*512 + lane*8;
      *(float4*)dst       = *(float4*)&y[0];
      *(float4*)(dst + 4) = *(float4*)&y[4];
    }
  }
}

extern "C" void kernel_launch(void* const* d_in, const int* in_sizes, int n_in,
                              void* d_out, int out_size, void* d_ws, size_t ws_size,
                              hipStream_t stream)
{
  unsigned short* q_bf  = (unsigned short*)d_ws;
  unsigned short* k_bf  = q_bf  + 8192l*512;
  unsigned short* vt_bf = k_bf  + 8192l*512;
  unsigned short* wt    = vt_bf + 8192l*512;
  unsigned short* qin   = wt + 4l*512*512;
  unsigned short* kin   = qin + 4194304;
  unsigned short* o_bf  = qin;   // alias: valid after proj_mfma

  hipLaunchKernelGGL(prep_inputs, dim3(4352), dim3(256), 0, stream,
                     (const float*)d_in[5], (const float*)d_in[7],
                     (const float*)d_in[9], (const float*)d_in[11],
                     (const float*)d_in[0], (const float*)d_in[1], wt, qin);
  hipLaunchKernelGGL(proj_mfma, dim3(4,64,3), dim3(256), 0, stream,
                     qin, kin, wt,
                     (const float*)d_in[6], (const float*)d_in[8],
                     (const float*)d_in[10], q_bf, k_bf, vt_bf);
  hipLaunchKernelGGL(attn_mfma, dim3(64,8), dim3(256), 0, stream,
                     q_bf, k_bf, vt_bf,
                     (const float*)d_in[2], (const float*)d_in[3], o_bf);
  hipLaunchKernelGGL(out_ln, dim3(256), dim3(512), 0, stream,
                     o_bf, wt + 3l*512*512, (const float*)d_in[12],
                     (const float*)d_in[13], (const float*)d_in[14],
                     (const float*)d_in[15], (const float*)d_in[16],
                     (float*)d_out);
}